// Round 1
// baseline (3187.790 us; speedup 1.0000x reference)
//
#include <hip/hip_runtime.h>
#include <hip/hip_bf16.h>
#include <math.h>

#define SEQ   2048
#define BATCH 4
#define NHID  1024
#define HEADS 16
#define DIM   64
#define MROWS (SEQ*BATCH)   // 8192

__device__ __forceinline__ float sigf(float x) { return 1.0f / (1.0f + expf(-x)); }

// ---------------- prep: cf[j] = sigmoid(vs_p) . vq_w[j] + vq_b[j], j in [0,2048)
// one wave per row; grid 512 x 256
__global__ __launch_bounds__(256) void k_cf(const float* __restrict__ vs_p,
                                            const float* __restrict__ vq_w,
                                            const float* __restrict__ vq_b,
                                            float* __restrict__ cf)
{
    const int wave = threadIdx.x >> 6, lane = threadIdx.x & 63;
    const int j = blockIdx.x * 4 + wave;          // 0..2047
    const float* w = vq_w + (size_t)j * NHID;
    float p = 0.f;
    for (int i = lane; i < NHID; i += 64) p += sigf(vs_p[i]) * w[i];
#pragma unroll
    for (int off = 32; off; off >>= 1) p += __shfl_down(p, off);
    if (lane == 0) cf[j] = p + vq_b[j];
}

// scale vectors: sq, sk, sv, rg  (1 block x 256)
__global__ __launch_bounds__(256) void k_scales(const float* __restrict__ qs_p,
                                                const float* __restrict__ ks_p,
                                                const float* __restrict__ r_gate,
                                                const float* __restrict__ cf,
                                                float* __restrict__ sq, float* __restrict__ sk,
                                                float* __restrict__ sv, float* __restrict__ rg)
{
    for (int n = threadIdx.x; n < NHID; n += 256) {
        sq[n] = sigf(qs_p[n]);
        sk[n] = sigf(ks_p[n]);
        rg[n] = sigf(r_gate[n]);
        sv[n] = sigf(cf[n + NHID]) * tanhf(cf[n]);
    }
}

// ---------------- projection GEMM: out[m,n] = scale[n]*(X[m,:].W[n,:] + bias[n])
// X: MROWS x K row-major, W: N x K row-major (so X @ W^T). Tile 128x128, BK=8.
#define BM 128
#define BN 128
#define BK 8

__global__ __launch_bounds__(256) void k_proj(const float* __restrict__ X,
                                              const float* __restrict__ W,
                                              const float* __restrict__ bias,
                                              const float* __restrict__ scale,
                                              float* __restrict__ out, int K)
{
    __shared__ float As[BK][BM];
    __shared__ float Bs[BK][BN];
    const int t = threadIdx.x;
    const int tx = t & 15, ty = t >> 4;
    const int bm = blockIdx.x, bn = blockIdx.y;
    const float* Xb = X + (size_t)bm * BM * K;
    const float* Wb = W + (size_t)bn * BN * K;
    const int r = t >> 1;           // 0..127
    const int c = (t & 1) * 4;      // 0 or 4
    float acc[8][8] = {};

    for (int k0 = 0; k0 < K; k0 += BK) {
        float4 xa = *(const float4*)(Xb + (size_t)r * K + k0 + c);
        float4 wb = *(const float4*)(Wb + (size_t)r * K + k0 + c);
        __syncthreads();
        As[c+0][r] = xa.x; As[c+1][r] = xa.y; As[c+2][r] = xa.z; As[c+3][r] = xa.w;
        Bs[c+0][r] = wb.x; Bs[c+1][r] = wb.y; Bs[c+2][r] = wb.z; Bs[c+3][r] = wb.w;
        __syncthreads();
#pragma unroll
        for (int k = 0; k < BK; ++k) {
            float a[8], b[8];
#pragma unroll
            for (int i = 0; i < 8; ++i) a[i] = As[k][ty*8 + i];
#pragma unroll
            for (int j = 0; j < 8; ++j) b[j] = Bs[k][tx*8 + j];
#pragma unroll
            for (int i = 0; i < 8; ++i)
#pragma unroll
                for (int j = 0; j < 8; ++j) acc[i][j] += a[i] * b[j];
        }
    }
#pragma unroll
    for (int i = 0; i < 8; ++i) {
        const int m = bm*BM + ty*8 + i;
#pragma unroll
        for (int j = 0; j < 8; ++j) {
            const int n = bn*BN + tx*8 + j;
            out[(size_t)m * NHID + n] = scale[n] * (acc[i][j] + bias[n]);
        }
    }
}

// ---------------- flash attention, fp32. grid (SEQ/32, BATCH*HEADS), 256 thr.
#define QT 32
#define KT 32

__global__ __launch_bounds__(256) void k_attn(const float* __restrict__ Qp,
                                              const float* __restrict__ Kp,
                                              const float* __restrict__ Vp,
                                              float* __restrict__ mixo)
{
    __shared__ float Qs[QT][DIM+4];
    __shared__ float Ks[KT][DIM+4];
    __shared__ float Vs[KT][DIM+4];
    __shared__ float Ss[QT][KT+1];
    const int t  = threadIdx.x;
    const int qt = blockIdx.x, bh = blockIdx.y;
    const int b  = bh >> 4, h = bh & 15;
    const int r  = t >> 3;          // q row in tile, 0..31
    const int dg = t & 7;           // 0..7
    const int d0 = dg * 8;

    {   // stage Q tile
        const float* src = Qp + ((size_t)((qt*QT + r)*BATCH + b))*NHID + h*DIM + d0;
        *(float4*)&Qs[r][d0]     = *(const float4*)src;
        *(float4*)&Qs[r][d0 + 4] = *(const float4*)(src + 4);
    }
    __syncthreads();
    float q[DIM];
#pragma unroll
    for (int d = 0; d < DIM; d += 4) {
        float4 v = *(const float4*)&Qs[r][d];
        q[d] = v.x; q[d+1] = v.y; q[d+2] = v.z; q[d+3] = v.w;
    }

    float acc[8] = {0,0,0,0,0,0,0,0};
    float m_i = -1e30f, l_i = 0.f;

    for (int j0 = 0; j0 < SEQ; j0 += KT) {
        __syncthreads();
        {   // stage K,V tiles
            const size_t off = ((size_t)((j0 + r)*BATCH + b))*NHID + h*DIM + d0;
            *(float4*)&Ks[r][d0]     = *(const float4*)(Kp + off);
            *(float4*)&Ks[r][d0 + 4] = *(const float4*)(Kp + off + 4);
            *(float4*)&Vs[r][d0]     = *(const float4*)(Vp + off);
            *(float4*)&Vs[r][d0 + 4] = *(const float4*)(Vp + off + 4);
        }
        __syncthreads();
#pragma unroll
        for (int jj = 0; jj < 4; ++jj) {
            const int j = dg + jj*8;
            float s = 0.f;
#pragma unroll
            for (int d = 0; d < DIM; d += 4) {
                float4 kv = *(const float4*)&Ks[j][d];
                s += q[d]*kv.x + q[d+1]*kv.y + q[d+2]*kv.z + q[d+3]*kv.w;
            }
            Ss[r][j] = s * 0.125f;
        }
        __syncthreads();
        float mt = m_i;
#pragma unroll
        for (int j = 0; j < KT; ++j) mt = fmaxf(mt, Ss[r][j]);
        const float corr = expf(m_i - mt);
        l_i *= corr;
#pragma unroll
        for (int d = 0; d < 8; ++d) acc[d] *= corr;
#pragma unroll
        for (int j = 0; j < KT; ++j) {
            const float p = expf(Ss[r][j] - mt);
            l_i += p;
            float4 v0 = *(const float4*)&Vs[j][d0];
            float4 v1 = *(const float4*)&Vs[j][d0 + 4];
            acc[0] += p*v0.x; acc[1] += p*v0.y; acc[2] += p*v0.z; acc[3] += p*v0.w;
            acc[4] += p*v1.x; acc[5] += p*v1.y; acc[6] += p*v1.z; acc[7] += p*v1.w;
        }
        m_i = mt;
    }
    const float inv = 1.f / l_i;
    float* dst = mixo + ((size_t)((qt*QT + r)*BATCH + b))*NHID + h*DIM + d0;
    *(float4*)dst       = make_float4(acc[0]*inv, acc[1]*inv, acc[2]*inv, acc[3]*inv);
    *(float4*)(dst + 4) = make_float4(acc[4]*inv, acc[5]*inv, acc[6]*inv, acc[7]*inv);
}

// ---------------- final GEMM over concat[mix, q_orig] (K=2048) + gelu/gate epilogue
__global__ __launch_bounds__(256) void k_final(const float* __restrict__ Xm,
                                               const float* __restrict__ Xq,
                                               const float* __restrict__ W,
                                               const float* __restrict__ bias,
                                               const float* __restrict__ rg,
                                               float* __restrict__ out)
{
    const int K = 2 * NHID;
    __shared__ float As[BK][BM];
    __shared__ float Bs[BK][BN];
    const int t = threadIdx.x;
    const int tx = t & 15, ty = t >> 4;
    const int bm = blockIdx.x, bn = blockIdx.y;
    const float* Wb = W + (size_t)bn * BN * K;
    const int r = t >> 1;
    const int c = (t & 1) * 4;
    float acc[8][8] = {};

    for (int k0 = 0; k0 < K; k0 += BK) {
        const int kk = k0 + c;
        const int row = bm*BM + r;
        const float* src = (kk < NHID) ? (Xm + (size_t)row*NHID + kk)
                                       : (Xq + (size_t)row*NHID + (kk - NHID));
        float4 xa = *(const float4*)src;
        float4 wb = *(const float4*)(Wb + (size_t)r * K + k0 + c);
        __syncthreads();
        As[c+0][r] = xa.x; As[c+1][r] = xa.y; As[c+2][r] = xa.z; As[c+3][r] = xa.w;
        Bs[c+0][r] = wb.x; Bs[c+1][r] = wb.y; Bs[c+2][r] = wb.z; Bs[c+3][r] = wb.w;
        __syncthreads();
#pragma unroll
        for (int k = 0; k < BK; ++k) {
            float a[8], b[8];
#pragma unroll
            for (int i = 0; i < 8; ++i) a[i] = As[k][ty*8 + i];
#pragma unroll
            for (int j = 0; j < 8; ++j) b[j] = Bs[k][tx*8 + j];
#pragma unroll
            for (int i = 0; i < 8; ++i)
#pragma unroll
                for (int j = 0; j < 8; ++j) acc[i][j] += a[i] * b[j];
        }
    }
#pragma unroll
    for (int i = 0; i < 8; ++i) {
        const int m = bm*BM + ty*8 + i;
#pragma unroll
        for (int j = 0; j < 8; ++j) {
            const int n = bn*BN + tx*8 + j;
            const float pre = acc[i][j] + bias[n];
            const float g = pre * sigf(1.702f * pre);
            out[(size_t)m * NHID + n] = rg[n] * Xm[(size_t)m*NHID + n] + g;
        }
    }
}

extern "C" void kernel_launch(void* const* d_in, const int* in_sizes, int n_in,
                              void* d_out, int out_size, void* d_ws, size_t ws_size,
                              hipStream_t stream)
{
    (void)in_sizes; (void)n_in; (void)out_size; (void)ws_size;
    const float* query  = (const float*)d_in[0];
    const float* key    = (const float*)d_in[1];
    const float* value  = (const float*)d_in[2];
    const float* qs_p   = (const float*)d_in[3];
    const float* ks_p   = (const float*)d_in[4];
    const float* vs_p   = (const float*)d_in[5];
    const float* vq_w   = (const float*)d_in[6];
    const float* vq_b   = (const float*)d_in[7];
    const float* q_w    = (const float*)d_in[8];
    const float* q_b    = (const float*)d_in[9];
    const float* k_w    = (const float*)d_in[10];
    const float* k_b    = (const float*)d_in[11];
    const float* v_w    = (const float*)d_in[12];
    const float* v_b    = (const float*)d_in[13];
    const float* r_w    = (const float*)d_in[14];
    const float* r_b    = (const float*)d_in[15];
    const float* r_gate = (const float*)d_in[16];

    float* ws  = (float*)d_ws;
    float* sq  = ws;
    float* sk  = ws + 1024;
    float* sv  = ws + 2048;
    float* rg  = ws + 3072;
    float* cf  = ws + 4096;              // 2048
    float* Qp  = ws + 8192;              // 8192*1024 each
    float* Kp  = Qp + (size_t)MROWS * NHID;
    float* Vp  = Kp + (size_t)MROWS * NHID;
    float* mixp= Vp + (size_t)MROWS * NHID;

    k_cf<<<dim3(512), dim3(256), 0, stream>>>(vs_p, vq_w, vq_b, cf);
    k_scales<<<dim3(1), dim3(256), 0, stream>>>(qs_p, ks_p, r_gate, cf, sq, sk, sv, rg);

    k_proj<<<dim3(MROWS/BM, NHID/BN), dim3(256), 0, stream>>>(query, q_w, q_b, sq, Qp, NHID);
    k_proj<<<dim3(MROWS/BM, NHID/BN), dim3(256), 0, stream>>>(key,   k_w, k_b, sk, Kp, NHID);
    k_proj<<<dim3(MROWS/BM, NHID/BN), dim3(256), 0, stream>>>(value, v_w, v_b, sv, Vp, NHID);

    k_attn<<<dim3(SEQ/QT, BATCH*HEADS), dim3(256), 0, stream>>>(Qp, Kp, Vp, mixp);

    k_final<<<dim3(MROWS/BM, NHID/BN), dim3(256), 0, stream>>>(mixp, Qp, r_w, r_b, rg,
                                                               (float*)d_out);
}

// Round 2
// 482.960 us; speedup vs baseline: 6.6005x; 6.6005x over previous
//
#include <hip/hip_runtime.h>
#include <hip/hip_bf16.h>
#include <math.h>

#define SEQ   2048
#define BATCH 4
#define NHID  1024
#define HEADS 16
#define DIM   64
#define MROWS (SEQ*BATCH)   // 8192
#define LOG2E 1.44269504f

typedef __attribute__((ext_vector_type(8))) short bf16x8;
typedef __attribute__((ext_vector_type(4))) float f32x4;

__device__ __forceinline__ float sigf(float x) { return 1.0f / (1.0f + expf(-x)); }

__device__ __forceinline__ unsigned short f2b(float x) {
    unsigned int u = __float_as_uint(x);
    return (unsigned short)((u + 0x7FFFu + ((u >> 16) & 1u)) >> 16);
}
__device__ __forceinline__ float b2f(unsigned short h) {
    return __uint_as_float(((unsigned int)h) << 16);
}
__device__ __forceinline__ void gload_lds16(const void* g, void* l) {
    __builtin_amdgcn_global_load_lds((const __attribute__((address_space(1))) void*)g,
                                     (__attribute__((address_space(3))) void*)l,
                                     16, 0, 0);
}

// ---------------- fp32 -> bf16 convert (vectorized), n multiple of 4
__global__ __launch_bounds__(256) void k_f2b(const float* __restrict__ src,
                                             unsigned short* __restrict__ dst, int n)
{
    int i = (blockIdx.x * 256 + threadIdx.x) * 4;
    if (i < n) {
        float4 v = *(const float4*)(src + i);
        unsigned short o0 = f2b(v.x), o1 = f2b(v.y), o2 = f2b(v.z), o3 = f2b(v.w);
        unsigned long long pack = (unsigned long long)o0 | ((unsigned long long)o1 << 16)
                                | ((unsigned long long)o2 << 32) | ((unsigned long long)o3 << 48);
        *(unsigned long long*)(dst + i) = pack;
    }
}

// ---------------- prep: cf[j] = sigmoid(vs_p) . vq_w[j] + vq_b[j]
__global__ __launch_bounds__(256) void k_cf(const float* __restrict__ vs_p,
                                            const float* __restrict__ vq_w,
                                            const float* __restrict__ vq_b,
                                            float* __restrict__ cf)
{
    const int wave = threadIdx.x >> 6, lane = threadIdx.x & 63;
    const int j = blockIdx.x * 4 + wave;
    const float* w = vq_w + (size_t)j * NHID;
    float p = 0.f;
    for (int i = lane; i < NHID; i += 64) p += sigf(vs_p[i]) * w[i];
#pragma unroll
    for (int off = 32; off; off >>= 1) p += __shfl_down(p, off);
    if (lane == 0) cf[j] = p + vq_b[j];
}

__global__ __launch_bounds__(256) void k_scales(const float* __restrict__ qs_p,
                                                const float* __restrict__ ks_p,
                                                const float* __restrict__ r_gate,
                                                const float* __restrict__ cf,
                                                float* __restrict__ sq, float* __restrict__ sk,
                                                float* __restrict__ sv, float* __restrict__ rg)
{
    for (int n = threadIdx.x; n < NHID; n += 256) {
        sq[n] = sigf(qs_p[n]);
        sk[n] = sigf(ks_p[n]);
        rg[n] = sigf(r_gate[n]);
        sv[n] = sigf(cf[n + NHID]) * tanhf(cf[n]);
    }
}

// ---------------- bf16 MFMA GEMM, 128x128 tile, BK=32, m97-style staging.
// A: [M][K] bf16 row-major.  B: [N][K] bf16 row-major (i.e. B^T layout).
// MODE 0: proj->Qc right half (bf16, row stride 2048, col 1024+n), val=scale[n]*(acc+bias[n])
// MODE 1: proj->KV[b][h][s][d] bf16, same val
// MODE 2: final: out fp32[m][n] = scale[n]*b2f(mixb[m*2048+n]) + gelu(acc+bias[n])
template<int MODE>
__global__ __launch_bounds__(256) void k_gemm(const unsigned short* __restrict__ A,
                                              const unsigned short* __restrict__ B,
                                              const float* __restrict__ bias,
                                              const float* __restrict__ scale,
                                              unsigned short* __restrict__ outb,
                                              float* __restrict__ outf,
                                              const unsigned short* __restrict__ mixb,
                                              int K)
{
    __shared__ unsigned short As[128 * 32];
    __shared__ unsigned short Bs[128 * 32];
    const int t = threadIdx.x;
    const int wid = t >> 6, lane = t & 63;
    const int wr = wid >> 1, wc = wid & 1;
    const int bm = blockIdx.x, bn = blockIdx.y;
    const unsigned short* Ab = A + (size_t)bm * 128 * K;
    const unsigned short* Bb = B + (size_t)bn * 128 * K;

    f32x4 acc[4][4] = {};

    const int srow = t >> 2;            // 0..63
    const int scol = (t & 3) * 8;       // ushort col within BK
    for (int k0 = 0; k0 < K; k0 += 32) {
        __syncthreads();
        gload_lds16(Ab + (size_t)srow * K + k0 + scol,        (char*)As + t * 16);
        gload_lds16(Ab + (size_t)(srow + 64) * K + k0 + scol, (char*)As + 4096 + t * 16);
        gload_lds16(Bb + (size_t)srow * K + k0 + scol,        (char*)Bs + t * 16);
        gload_lds16(Bb + (size_t)(srow + 64) * K + k0 + scol, (char*)Bs + 4096 + t * 16);
        __syncthreads();
        bf16x8 af[4], bf[4];
#pragma unroll
        for (int mi = 0; mi < 4; ++mi)
            af[mi] = *(const bf16x8*)&As[(wr * 64 + mi * 16 + (lane & 15)) * 32 + (lane >> 4) * 8];
#pragma unroll
        for (int ni = 0; ni < 4; ++ni)
            bf[ni] = *(const bf16x8*)&Bs[(wc * 64 + ni * 16 + (lane & 15)) * 32 + (lane >> 4) * 8];
#pragma unroll
        for (int mi = 0; mi < 4; ++mi)
#pragma unroll
            for (int ni = 0; ni < 4; ++ni)
                acc[mi][ni] = __builtin_amdgcn_mfma_f32_16x16x32_bf16(af[mi], bf[ni], acc[mi][ni], 0, 0, 0);
    }

#pragma unroll
    for (int mi = 0; mi < 4; ++mi) {
#pragma unroll
        for (int r = 0; r < 4; ++r) {
            const int m = bm * 128 + wr * 64 + mi * 16 + (lane >> 4) * 4 + r;
#pragma unroll
            for (int ni = 0; ni < 4; ++ni) {
                const int n = bn * 128 + wc * 64 + ni * 16 + (lane & 15);
                const float a = acc[mi][ni][r];
                if constexpr (MODE == 0) {
                    const float v = scale[n] * (a + bias[n]);
                    outb[(size_t)m * 2048 + 1024 + n] = f2b(v);
                } else if constexpr (MODE == 1) {
                    const float v = scale[n] * (a + bias[n]);
                    const int s = m >> 2, b = m & 3, h = n >> 6, d = n & 63;
                    outb[((size_t)(b * HEADS + h) * SEQ + s) * DIM + d] = f2b(v);
                } else {
                    const float pre = a + bias[n];
                    const float g = pre * sigf(1.702f * pre);
                    const float mx = b2f(mixb[(size_t)m * 2048 + n]);
                    outf[(size_t)m * NHID + n] = scale[n] * mx + g;
                }
            }
        }
    }
}

// ---------------- MFMA flash attention. grid (SEQ/64, BATCH*HEADS), 256 thr (4 waves).
// Qc: [8192][2048] bf16, q at cols 1024..2047; mix written to cols 0..1023.
// Kb/Vb: [b*16+h][2048][64] bf16.
__global__ __launch_bounds__(256) void k_attn(const unsigned short* __restrict__ Qc,
                                              const unsigned short* __restrict__ Kb,
                                              const unsigned short* __restrict__ Vb,
                                              unsigned short* __restrict__ mixo)
{
    __shared__ unsigned short Qs[64][72];
    __shared__ unsigned short Ks[64][72];
    __shared__ unsigned short Vt[64][72];       // Vt[d][swizzled s]
    __shared__ unsigned short Pw[4][16][72];
    const int t = threadIdx.x, wid = t >> 6, lane = t & 63;
    const int qt = blockIdx.x;
    const int bh = blockIdx.y;
    const int b = bh >> 4, h = bh & 15;
    const int lg = lane >> 4, ll = lane & 15;

    // stage Q tile (rows s = qt*64+row)
#pragma unroll
    for (int it = 0; it < 2; ++it) {
        const int idx = t + it * 256;
        const int row = idx >> 3, d0 = (idx & 7) * 8;
        const int s = qt * 64 + row;
        bf16x8 v = *(const bf16x8*)&Qc[(size_t)(s * 4 + b) * 2048 + 1024 + h * 64 + d0];
        *(bf16x8*)&Qs[row][d0] = v;
    }
    __syncthreads();
    bf16x8 qf[2];
    qf[0] = *(const bf16x8*)&Qs[wid * 16 + ll][lg * 8];
    qf[1] = *(const bf16x8*)&Qs[wid * 16 + ll][32 + lg * 8];

    f32x4 accO[4] = {};
    float m_r[4], l_r[4];
#pragma unroll
    for (int r = 0; r < 4; ++r) { m_r[r] = -1e30f; l_r[r] = 0.f; }

    const unsigned short* Kbh = Kb + (size_t)bh * SEQ * DIM;
    const unsigned short* Vbh = Vb + (size_t)bh * SEQ * DIM;

    for (int j0 = 0; j0 < SEQ; j0 += 64) {
        __syncthreads();
#pragma unroll
        for (int it = 0; it < 2; ++it) {
            const int idx = t + it * 256;
            const int row = idx >> 3, d0 = (idx & 7) * 8;
            bf16x8 kv = *(const bf16x8*)&Kbh[(size_t)(j0 + row) * DIM + d0];
            *(bf16x8*)&Ks[row][d0] = kv;
            bf16x8 vv = *(const bf16x8*)&Vbh[(size_t)(j0 + row) * DIM + d0];
            const int pc = (((row >> 3) ^ (d0 >> 3)) & 7) * 8 + (row & 7);
#pragma unroll
            for (int i = 0; i < 8; ++i) Vt[d0 + i][pc] = (unsigned short)vv[i];
        }
        __syncthreads();

        // S = Q K^T  (per wave: 16 q-rows x 64 j)
        f32x4 sf[4] = {};
#pragma unroll
        for (int jj = 0; jj < 4; ++jj) {
            bf16x8 kf0 = *(const bf16x8*)&Ks[jj * 16 + ll][lg * 8];
            bf16x8 kf1 = *(const bf16x8*)&Ks[jj * 16 + ll][32 + lg * 8];
            sf[jj] = __builtin_amdgcn_mfma_f32_16x16x32_bf16(qf[0], kf0, sf[jj], 0, 0, 0);
            sf[jj] = __builtin_amdgcn_mfma_f32_16x16x32_bf16(qf[1], kf1, sf[jj], 0, 0, 0);
        }

        // online softmax (rows (lg*4+r), cols ll+16*jj)
        float sc[4][4];
#pragma unroll
        for (int r = 0; r < 4; ++r)
#pragma unroll
            for (int jj = 0; jj < 4; ++jj) sc[r][jj] = sf[jj][r] * 0.125f;
        float mt[4];
#pragma unroll
        for (int r = 0; r < 4; ++r)
            mt[r] = fmaxf(fmaxf(sc[r][0], sc[r][1]), fmaxf(sc[r][2], sc[r][3]));
#pragma unroll
        for (int off = 1; off < 16; off <<= 1)
#pragma unroll
            for (int r = 0; r < 4; ++r) mt[r] = fmaxf(mt[r], __shfl_xor(mt[r], off));
        float corr[4], padd[4];
#pragma unroll
        for (int r = 0; r < 4; ++r) {
            const float mn = fmaxf(m_r[r], mt[r]);
            corr[r] = exp2f((m_r[r] - mn) * LOG2E);
            m_r[r] = mn;
            padd[r] = 0.f;
        }
        unsigned short pb[4][4];
#pragma unroll
        for (int r = 0; r < 4; ++r)
#pragma unroll
            for (int jj = 0; jj < 4; ++jj) {
                const float p = exp2f((sc[r][jj] - m_r[r]) * LOG2E);
                padd[r] += p;
                pb[r][jj] = f2b(p);
            }
#pragma unroll
        for (int off = 1; off < 16; off <<= 1)
#pragma unroll
            for (int r = 0; r < 4; ++r) padd[r] += __shfl_xor(padd[r], off);
#pragma unroll
        for (int r = 0; r < 4; ++r) l_r[r] = l_r[r] * corr[r] + padd[r];
#pragma unroll
        for (int dj = 0; dj < 4; ++dj)
#pragma unroll
            for (int r = 0; r < 4; ++r) accO[dj][r] *= corr[r];

        // P -> per-wave LDS, then PV
#pragma unroll
        for (int r = 0; r < 4; ++r)
#pragma unroll
            for (int jj = 0; jj < 4; ++jj)
                Pw[wid][lg * 4 + r][ll + jj * 16] = pb[r][jj];

#pragma unroll
        for (int kk = 0; kk < 2; ++kk) {
            bf16x8 pf = *(const bf16x8*)&Pw[wid][ll][kk * 32 + lg * 8];
#pragma unroll
            for (int dj = 0; dj < 4; ++dj) {
                const int d = dj * 16 + ll;
                const int pbk = ((kk * 4 + lg) ^ ((d >> 3) & 7));
                bf16x8 vf = *(const bf16x8*)&Vt[d][pbk * 8];
                accO[dj] = __builtin_amdgcn_mfma_f32_16x16x32_bf16(pf, vf, accO[dj], 0, 0, 0);
            }
        }
    }

    // epilogue: mix = accO / l
#pragma unroll
    for (int r = 0; r < 4; ++r) {
        const float inv = 1.f / l_r[r];
        const int s = qt * 64 + wid * 16 + lg * 4 + r;
#pragma unroll
        for (int dj = 0; dj < 4; ++dj) {
            const int d = dj * 16 + ll;
            mixo[(size_t)(s * 4 + b) * 2048 + h * 64 + d] = f2b(accO[dj][r] * inv);
        }
    }
}

extern "C" void kernel_launch(void* const* d_in, const int* in_sizes, int n_in,
                              void* d_out, int out_size, void* d_ws, size_t ws_size,
                              hipStream_t stream)
{
    (void)in_sizes; (void)n_in; (void)out_size; (void)ws_size;
    const float* query  = (const float*)d_in[0];
    const float* key    = (const float*)d_in[1];
    const float* value  = (const float*)d_in[2];
    const float* qs_p   = (const float*)d_in[3];
    const float* ks_p   = (const float*)d_in[4];
    const float* vs_p   = (const float*)d_in[5];
    const float* vq_w   = (const float*)d_in[6];
    const float* vq_b   = (const float*)d_in[7];
    const float* q_w    = (const float*)d_in[8];
    const float* q_b    = (const float*)d_in[9];
    const float* k_w    = (const float*)d_in[10];
    const float* k_b    = (const float*)d_in[11];
    const float* v_w    = (const float*)d_in[12];
    const float* v_b    = (const float*)d_in[13];
    const float* r_w    = (const float*)d_in[14];
    const float* r_b    = (const float*)d_in[15];
    const float* r_gate = (const float*)d_in[16];

    float* fws = (float*)d_ws;
    float* sq = fws;
    float* sk = fws + 1024;
    float* sv = fws + 2048;
    float* rg = fws + 3072;
    float* cf = fws + 4096;                 // 2048 floats

    unsigned short* uws = (unsigned short*)(fws + 8192);
    unsigned short* Xq = uws;                                   // 8192*1024
    unsigned short* Xk = Xq + (size_t)MROWS * NHID;
    unsigned short* Xv = Xk + (size_t)MROWS * NHID;
    unsigned short* Wq = Xv + (size_t)MROWS * NHID;             // 1024*1024
    unsigned short* Wk = Wq + (size_t)NHID * NHID;
    unsigned short* Wv = Wk + (size_t)NHID * NHID;
    unsigned short* Wr = Wv + (size_t)NHID * NHID;              // 1024*2048
    unsigned short* Qc = Wr + (size_t)NHID * 2 * NHID;          // 8192*2048
    unsigned short* Kb = Qc + (size_t)MROWS * 2 * NHID;         // 64*2048*64
    unsigned short* Vb = Kb + (size_t)BATCH * HEADS * SEQ * DIM;

    k_cf<<<dim3(512), dim3(256), 0, stream>>>(vs_p, vq_w, vq_b, cf);
    k_scales<<<dim3(1), dim3(256), 0, stream>>>(qs_p, ks_p, r_gate, cf, sq, sk, sv, rg);

    const int NIN = MROWS * NHID;           // 8388608
    k_f2b<<<dim3(NIN / 1024), dim3(256), 0, stream>>>(query, Xq, NIN);
    k_f2b<<<dim3(NIN / 1024), dim3(256), 0, stream>>>(key,   Xk, NIN);
    k_f2b<<<dim3(NIN / 1024), dim3(256), 0, stream>>>(value, Xv, NIN);
    k_f2b<<<dim3(1024), dim3(256), 0, stream>>>(q_w, Wq, NHID * NHID);
    k_f2b<<<dim3(1024), dim3(256), 0, stream>>>(k_w, Wk, NHID * NHID);
    k_f2b<<<dim3(1024), dim3(256), 0, stream>>>(v_w, Wv, NHID * NHID);
    k_f2b<<<dim3(2048), dim3(256), 0, stream>>>(r_w, Wr, NHID * 2 * NHID);

    k_gemm<0><<<dim3(64, 8), dim3(256), 0, stream>>>(Xq, Wq, q_b, sq, Qc, nullptr, nullptr, NHID);
    k_gemm<1><<<dim3(64, 8), dim3(256), 0, stream>>>(Xk, Wk, k_b, sk, Kb, nullptr, nullptr, NHID);
    k_gemm<1><<<dim3(64, 8), dim3(256), 0, stream>>>(Xv, Wv, v_b, sv, Vb, nullptr, nullptr, NHID);

    k_attn<<<dim3(SEQ / 64, BATCH * HEADS), dim3(256), 0, stream>>>(Qc, Kb, Vb, Qc);

    k_gemm<2><<<dim3(64, 8), dim3(256), 0, stream>>>(Qc, Wr, r_b, rg, nullptr, (float*)d_out, Qc, 2 * NHID);
}

// Round 5
// 377.814 us; speedup vs baseline: 8.4375x; 1.2783x over previous
//
#include <hip/hip_runtime.h>
#include <hip/hip_bf16.h>
#include <math.h>

#define SEQ   2048
#define BATCH 4
#define NHID  1024
#define HEADS 16
#define DIM   64
#define MROWS (SEQ*BATCH)   // 8192
#define LOG2E 1.44269504f

typedef __attribute__((ext_vector_type(8)))  short bf16x8;
typedef __attribute__((ext_vector_type(4)))  float f32x4;
typedef __attribute__((ext_vector_type(16))) float f32x16;

__device__ __forceinline__ float sigf(float x) { return 1.0f / (1.0f + expf(-x)); }

__device__ __forceinline__ unsigned short f2b(float x) {
    unsigned int u = __float_as_uint(x);
    return (unsigned short)((u + 0x7FFFu + ((u >> 16) & 1u)) >> 16);
}
__device__ __forceinline__ float b2f(unsigned short h) {
    return __uint_as_float(((unsigned int)h) << 16);
}
__device__ __forceinline__ void gload_lds16(const void* g, void* l) {
    __builtin_amdgcn_global_load_lds((const __attribute__((address_space(1))) void*)g,
                                     (__attribute__((address_space(3))) void*)l,
                                     16, 0, 0);
}

// ---------------- fp32 -> bf16 convert (vectorized), n multiple of 4
__global__ __launch_bounds__(256) void k_f2b(const float* __restrict__ src,
                                             unsigned short* __restrict__ dst, int n)
{
    int i = (blockIdx.x * 256 + threadIdx.x) * 4;
    if (i < n) {
        float4 v = *(const float4*)(src + i);
        unsigned short o0 = f2b(v.x), o1 = f2b(v.y), o2 = f2b(v.z), o3 = f2b(v.w);
        unsigned long long pack = (unsigned long long)o0 | ((unsigned long long)o1 << 16)
                                | ((unsigned long long)o2 << 32) | ((unsigned long long)o3 << 48);
        *(unsigned long long*)(dst + i) = pack;
    }
}

// ---------------- prep: cf[j] = sigmoid(vs_p) . vq_w[j] + vq_b[j]
__global__ __launch_bounds__(256) void k_cf(const float* __restrict__ vs_p,
                                            const float* __restrict__ vq_w,
                                            const float* __restrict__ vq_b,
                                            float* __restrict__ cf)
{
    const int wave = threadIdx.x >> 6, lane = threadIdx.x & 63;
    const int j = blockIdx.x * 4 + wave;
    const float* w = vq_w + (size_t)j * NHID;
    float p = 0.f;
    for (int i = lane; i < NHID; i += 64) p += sigf(vs_p[i]) * w[i];
#pragma unroll
    for (int off = 32; off; off >>= 1) p += __shfl_down(p, off);
    if (lane == 0) cf[j] = p + vq_b[j];
}

// sk carries 0.125 (1/sqrt(dim)) and log2(e): softmax done in base-2 domain.
__global__ __launch_bounds__(256) void k_scales(const float* __restrict__ qs_p,
                                                const float* __restrict__ ks_p,
                                                const float* __restrict__ r_gate,
                                                const float* __restrict__ cf,
                                                float* __restrict__ sq, float* __restrict__ sk,
                                                float* __restrict__ sv, float* __restrict__ rg)
{
    for (int n = threadIdx.x; n < NHID; n += 256) {
        sq[n] = sigf(qs_p[n]);
        sk[n] = sigf(ks_p[n]) * (0.125f * LOG2E);
        rg[n] = sigf(r_gate[n]);
        sv[n] = sigf(cf[n + NHID]) * tanhf(cf[n]);
    }
}

// ---------------- bf16 MFMA GEMM, 128x128 tile, BK=32, m97-style staging.
// A: [M][K] bf16 row-major.  B: [N][K] bf16 row-major (i.e. B^T layout).
// MODE 0: proj-> Qc right half (col 1024+n) AND Qa[bh][s][d]
// MODE 1: proj-> K [b*16+h][s][d] bf16
// MODE 3: proj-> V^T [b*16+h][d][s] bf16
// MODE 2: final: out fp32[m][n] = scale[n]*b2f(mixb[m*2048+n]) + gelu(acc+bias[n])
template<int MODE>
__global__ __launch_bounds__(256) void k_gemm(const unsigned short* __restrict__ A,
                                              const unsigned short* __restrict__ B,
                                              const float* __restrict__ bias,
                                              const float* __restrict__ scale,
                                              unsigned short* __restrict__ outb,
                                              unsigned short* __restrict__ outb2,
                                              float* __restrict__ outf,
                                              const unsigned short* __restrict__ mixb,
                                              int K)
{
    __shared__ unsigned short As[128 * 32];
    __shared__ unsigned short Bs[128 * 32];
    const int t = threadIdx.x;
    const int wid = t >> 6, lane = t & 63;
    const int wr = wid >> 1, wc = wid & 1;
    const int bm = blockIdx.x, bn = blockIdx.y;
    const unsigned short* Ab = A + (size_t)bm * 128 * K;
    const unsigned short* Bb = B + (size_t)bn * 128 * K;

    f32x4 acc[4][4] = {};

    const int srow = t >> 2;            // 0..63
    const int scol = (t & 3) * 8;       // ushort col within BK
    for (int k0 = 0; k0 < K; k0 += 32) {
        __syncthreads();
        gload_lds16(Ab + (size_t)srow * K + k0 + scol,        (char*)As + t * 16);
        gload_lds16(Ab + (size_t)(srow + 64) * K + k0 + scol, (char*)As + 4096 + t * 16);
        gload_lds16(Bb + (size_t)srow * K + k0 + scol,        (char*)Bs + t * 16);
        gload_lds16(Bb + (size_t)(srow + 64) * K + k0 + scol, (char*)Bs + 4096 + t * 16);
        __syncthreads();
        bf16x8 af[4], bf[4];
#pragma unroll
        for (int mi = 0; mi < 4; ++mi)
            af[mi] = *(const bf16x8*)&As[(wr * 64 + mi * 16 + (lane & 15)) * 32 + (lane >> 4) * 8];
#pragma unroll
        for (int ni = 0; ni < 4; ++ni)
            bf[ni] = *(const bf16x8*)&Bs[(wc * 64 + ni * 16 + (lane & 15)) * 32 + (lane >> 4) * 8];
#pragma unroll
        for (int mi = 0; mi < 4; ++mi)
#pragma unroll
            for (int ni = 0; ni < 4; ++ni)
                acc[mi][ni] = __builtin_amdgcn_mfma_f32_16x16x32_bf16(af[mi], bf[ni], acc[mi][ni], 0, 0, 0);
    }

#pragma unroll
    for (int mi = 0; mi < 4; ++mi) {
#pragma unroll
        for (int r = 0; r < 4; ++r) {
            const int m = bm * 128 + wr * 64 + mi * 16 + (lane >> 4) * 4 + r;
#pragma unroll
            for (int ni = 0; ni < 4; ++ni) {
                const int n = bn * 128 + wc * 64 + ni * 16 + (lane & 15);
                const float a = acc[mi][ni][r];
                if constexpr (MODE == 0) {
                    const float v = scale[n] * (a + bias[n]);
                    const int s = m >> 2, b = m & 3, h = n >> 6, d = n & 63;
                    outb[(size_t)m * 2048 + 1024 + n] = f2b(v);
                    outb2[((size_t)(b * HEADS + h) * SEQ + s) * DIM + d] = f2b(v);
                } else if constexpr (MODE == 1) {
                    const float v = scale[n] * (a + bias[n]);
                    const int s = m >> 2, b = m & 3, h = n >> 6, d = n & 63;
                    outb[((size_t)(b * HEADS + h) * SEQ + s) * DIM + d] = f2b(v);
                } else if constexpr (MODE == 3) {
                    const float v = scale[n] * (a + bias[n]);
                    const int s = m >> 2, b = m & 3, h = n >> 6, d = n & 63;
                    outb[((size_t)(b * HEADS + h) * DIM + d) * SEQ + s] = f2b(v);
                } else {
                    const float pre = a + bias[n];
                    const float g = pre * sigf(1.702f * pre);
                    const float mx = b2f(mixb[(size_t)m * 2048 + n]);
                    outf[(size_t)m * NHID + n] = scale[n] * mx + g;
                }
            }
        }
    }
}

// ---------------- MFMA flash attention, swapped-operand 32x32 structure.
// grid (SEQ/128, BATCH*HEADS), 256 thr = 4 waves x 32 q-rows.
// Qa: [bh][s][d], Kb: [bh][s][d], Vt: [bh][d][s]  (K pre-scaled by 0.125*log2e).
// mix written as bf16 into Qc[8192][2048] cols 0..1023.
//
// QK^T (swapped): S^T[j][q] = mfma(A=K[j][k], B=Q^T[k][q]).
// PV  (swapped): mix^T[d][q] = mfma(A=V^T[d][j], B=P^T[j][q]) with P routed
// through per-wave LDS so B-fragment k-runs are plain contiguous b128 reads.
__global__ __launch_bounds__(256) void k_attn(const unsigned short* __restrict__ Qa,
                                              const unsigned short* __restrict__ Kb,
                                              const unsigned short* __restrict__ Vt,
                                              unsigned short* __restrict__ mixo)
{
    __shared__ unsigned short Ks[64][72];      // K[j][d]
    __shared__ unsigned short Vs[64][72];      // V^T[d][j-local]
    __shared__ unsigned short Pw[4][32][72];   // per-wave P[q][j-local]
    const int t = threadIdx.x, wid = t >> 6, l = t & 63;
    const int g2 = l >> 5, q31 = l & 31;
    const int bh = blockIdx.y, b = bh >> 4, h = bh & 15;
    const int s_q = blockIdx.x * 128 + wid * 32 + q31;   // this lane's q row

    const unsigned short* Kbh = Kb + (size_t)bh * SEQ * DIM;
    const unsigned short* Vbh = Vt + (size_t)bh * DIM * SEQ;
    const unsigned short* Qbh = Qa + (size_t)bh * SEQ * DIM;

    bf16x8 qf[4];
#pragma unroll
    for (int ds_ = 0; ds_ < 4; ++ds_)
        qf[ds_] = *(const bf16x8*)&Qbh[(size_t)s_q * DIM + ds_ * 16 + g2 * 8];

    f32x16 accO0 = {}, accO1 = {};             // d rows 0..31 / 32..63
    float m_r = -1e30f, l_r = 0.f;

    const int srow = t >> 2;                   // 0..63
    const int sc   = (t & 3) * 16;             // 0,16,32,48

    for (int j0 = 0; j0 < SEQ; j0 += 64) {
        __syncthreads();
        *(bf16x8*)&Ks[srow][sc]     = *(const bf16x8*)&Kbh[(size_t)(j0 + srow) * DIM + sc];
        *(bf16x8*)&Ks[srow][sc + 8] = *(const bf16x8*)&Kbh[(size_t)(j0 + srow) * DIM + sc + 8];
        *(bf16x8*)&Vs[srow][sc]     = *(const bf16x8*)&Vbh[(size_t)srow * SEQ + j0 + sc];
        *(bf16x8*)&Vs[srow][sc + 8] = *(const bf16x8*)&Vbh[(size_t)srow * SEQ + j0 + sc + 8];
        __syncthreads();

        // ---- QK^T: S^T[j][q]; lane = col q31; A rows j = l&31 (+32 for sB)
        f32x16 sA = {}, sB = {};
#pragma unroll
        for (int ds_ = 0; ds_ < 4; ++ds_) {
            bf16x8 kf0 = *(const bf16x8*)&Ks[q31     ][ds_ * 16 + g2 * 8];
            bf16x8 kf1 = *(const bf16x8*)&Ks[32 + q31][ds_ * 16 + g2 * 8];
            sA = __builtin_amdgcn_mfma_f32_32x32x16_bf16(kf0, qf[ds_], sA, 0, 0, 0);
            sB = __builtin_amdgcn_mfma_f32_32x32x16_bf16(kf1, qf[ds_], sB, 0, 0, 0);
        }

        // ---- in-register online softmax (base-2 domain; scale folded into K)
        float mt = fmaxf(sA[0], sB[0]);
#pragma unroll
        for (int i = 1; i < 16; ++i) mt = fmaxf(mt, fmaxf(sA[i], sB[i]));
        mt = fmaxf(mt, __shfl_xor(mt, 32));
        const float mn = fmaxf(m_r, mt);
        const float corr = exp2f(m_r - mn);
        m_r = mn;

        float pv[32];
        float psum = 0.f;
#pragma unroll
        for (int i = 0; i < 16; ++i) { pv[i]      = exp2f(sA[i] - mn); psum += pv[i]; }
#pragma unroll
        for (int i = 0; i < 16; ++i) { pv[16 + i] = exp2f(sB[i] - mn); psum += pv[16 + i]; }
        psum += __shfl_xor(psum, 32);
        l_r = l_r * corr + psum;
        accO0 = accO0 * corr;
        accO1 = accO1 * corr;

        // ---- P -> per-wave LDS as P[q][j-local] bf16 (u32 pair writes).
        // reg pair (2p,2p+1) of sA holds rows j = jp, jp+1 with
        // jp = (2p&3) + 8*(p>>1) + 4*g2;  sB the same + 32.
#pragma unroll
        for (int p = 0; p < 8; ++p) {
            const int jp = (2 * p & 3) + 8 * (p >> 1) + 4 * g2;
            unsigned w = (unsigned)f2b(pv[2 * p]) | ((unsigned)f2b(pv[2 * p + 1]) << 16);
            *(unsigned*)&Pw[wid][q31][jp] = w;
        }
#pragma unroll
        for (int p = 0; p < 8; ++p) {
            const int jp = 32 + (2 * p & 3) + 8 * (p >> 1) + 4 * g2;
            unsigned w = (unsigned)f2b(pv[16 + 2 * p]) | ((unsigned)f2b(pv[16 + 2 * p + 1]) << 16);
            *(unsigned*)&Pw[wid][q31][jp] = w;
        }

        // ---- PV: mix^T[d][q] += V^T x P^T; all operands contiguous b128
#pragma unroll
        for (int kc = 0; kc < 4; ++kc) {
            bf16x8 pf  = *(const bf16x8*)&Pw[wid][q31][kc * 16 + g2 * 8];
            bf16x8 vf0 = *(const bf16x8*)&Vs[q31     ][kc * 16 + g2 * 8];
            bf16x8 vf1 = *(const bf16x8*)&Vs[32 + q31][kc * 16 + g2 * 8];
            accO0 = __builtin_amdgcn_mfma_f32_32x32x16_bf16(vf0, pf, accO0, 0, 0, 0);
            accO1 = __builtin_amdgcn_mfma_f32_32x32x16_bf16(vf1, pf, accO1, 0, 0, 0);
        }
    }

    // ---- epilogue: mix[q][d] = accO^T / l   (C/D: col=q31, row=d)
    const float inv = 1.f / l_r;
    unsigned short* dst = mixo + (size_t)(s_q * 4 + b) * 2048 + h * 64;
#pragma unroll
    for (int reg = 0; reg < 16; reg += 2) {
        const int d0a = (reg & 3) + 8 * (reg >> 2) + 4 * g2;
        unsigned w0 = (unsigned)f2b(accO0[reg] * inv) | ((unsigned)f2b(accO0[reg + 1] * inv) << 16);
        unsigned w1 = (unsigned)f2b(accO1[reg] * inv) | ((unsigned)f2b(accO1[reg + 1] * inv) << 16);
        *(unsigned*)&dst[d0a]      = w0;
        *(unsigned*)&dst[32 + d0a] = w1;
    }
}

extern "C" void kernel_launch(void* const* d_in, const int* in_sizes, int n_in,
                              void* d_out, int out_size, void* d_ws, size_t ws_size,
                              hipStream_t stream)
{
    (void)in_sizes; (void)n_in; (void)out_size; (void)ws_size;
    const float* query  = (const float*)d_in[0];
    const float* key    = (const float*)d_in[1];
    const float* value  = (const float*)d_in[2];
    const float* qs_p   = (const float*)d_in[3];
    const float* ks_p   = (const float*)d_in[4];
    const float* vs_p   = (const float*)d_in[5];
    const float* vq_w   = (const float*)d_in[6];
    const float* vq_b   = (const float*)d_in[7];
    const float* q_w    = (const float*)d_in[8];
    const float* q_b    = (const float*)d_in[9];
    const float* k_w    = (const float*)d_in[10];
    const float* k_b    = (const float*)d_in[11];
    const float* v_w    = (const float*)d_in[12];
    const float* v_b    = (const float*)d_in[13];
    const float* r_w    = (const float*)d_in[14];
    const float* r_b    = (const float*)d_in[15];
    const float* r_gate = (const float*)d_in[16];

    float* fws = (float*)d_ws;
    float* sq = fws;
    float* sk = fws + 1024;
    float* sv = fws + 2048;
    float* rg = fws + 3072;
    float* cf = fws + 4096;                 // 2048 floats

    unsigned short* uws = (unsigned short*)(fws + 8192);
    unsigned short* Xq = uws;                                   // 8192*1024
    unsigned short* Xk = Xq + (size_t)MROWS * NHID;
    unsigned short* Xv = Xk + (size_t)MROWS * NHID;
    unsigned short* Wq = Xv + (size_t)MROWS * NHID;             // 1024*1024
    unsigned short* Wk = Wq + (size_t)NHID * NHID;
    unsigned short* Wv = Wk + (size_t)NHID * NHID;
    unsigned short* Wr = Wv + (size_t)NHID * NHID;              // 1024*2048
    unsigned short* Qc = Wr + (size_t)NHID * 2 * NHID;          // 8192*2048
    unsigned short* Kb = Qc + (size_t)MROWS * 2 * NHID;         // 64*2048*64
    unsigned short* Vb = Kb + (size_t)BATCH * HEADS * SEQ * DIM;
    unsigned short* Qa = Xk;   // aliases Xk (dead after K-projection)

    k_cf<<<dim3(512), dim3(256), 0, stream>>>(vs_p, vq_w, vq_b, cf);
    k_scales<<<dim3(1), dim3(256), 0, stream>>>(qs_p, ks_p, r_gate, cf, sq, sk, sv, rg);

    const int NIN = MROWS * NHID;           // 8388608
    k_f2b<<<dim3(NIN / 1024), dim3(256), 0, stream>>>(query, Xq, NIN);
    k_f2b<<<dim3(NIN / 1024), dim3(256), 0, stream>>>(key,   Xk, NIN);
    k_f2b<<<dim3(NIN / 1024), dim3(256), 0, stream>>>(value, Xv, NIN);
    k_f2b<<<dim3(1024), dim3(256), 0, stream>>>(q_w, Wq, NHID * NHID);
    k_f2b<<<dim3(1024), dim3(256), 0, stream>>>(k_w, Wk, NHID * NHID);
    k_f2b<<<dim3(1024), dim3(256), 0, stream>>>(v_w, Wv, NHID * NHID);
    k_f2b<<<dim3(2048), dim3(256), 0, stream>>>(r_w, Wr, NHID * 2 * NHID);

    // K and V projections first (they consume Xk/Xv); Q last, writing Qa over Xk.
    k_gemm<1><<<dim3(64, 8), dim3(256), 0, stream>>>(Xk, Wk, k_b, sk, Kb, nullptr, nullptr, nullptr, NHID);
    k_gemm<3><<<dim3(64, 8), dim3(256), 0, stream>>>(Xv, Wv, v_b, sv, Vb, nullptr, nullptr, nullptr, NHID);
    k_gemm<0><<<dim3(64, 8), dim3(256), 0, stream>>>(Xq, Wq, q_b, sq, Qc, Qa, nullptr, nullptr, NHID);

    k_attn<<<dim3(SEQ / 128, BATCH * HEADS), dim3(256), 0, stream>>>(Qa, Kb, Vb, Qc);

    k_gemm<2><<<dim3(64, 8), dim3(256), 0, stream>>>(Qc, Wr, r_b, rg, nullptr, nullptr, (float*)d_out, Qc, 2 * NHID);
}

// Round 6
// 369.319 us; speedup vs baseline: 8.6315x; 1.0230x over previous
//
#include <hip/hip_runtime.h>
#include <hip/hip_bf16.h>
#include <math.h>

#define SEQ   2048
#define BATCH 4
#define NHID  1024
#define HEADS 16
#define DIM   64
#define MROWS (SEQ*BATCH)   // 8192
#define LOG2E 1.44269504f

typedef __attribute__((ext_vector_type(8)))  short bf16x8;
typedef __attribute__((ext_vector_type(4)))  float f32x4;
typedef __attribute__((ext_vector_type(16))) float f32x16;

__device__ __forceinline__ float sigf(float x) { return 1.0f / (1.0f + expf(-x)); }

__device__ __forceinline__ unsigned short f2b(float x) {
    unsigned int u = __float_as_uint(x);
    return (unsigned short)((u + 0x7FFFu + ((u >> 16) & 1u)) >> 16);
}
__device__ __forceinline__ float b2f(unsigned short h) {
    return __uint_as_float(((unsigned int)h) << 16);
}
__device__ __forceinline__ unsigned pk2(float lo, float hi) {
    __hip_bfloat162 h = __float22bfloat162_rn(make_float2(lo, hi));
    union { __hip_bfloat162 h; unsigned u; } cv; cv.h = h;
    return cv.u;
}
__device__ __forceinline__ void gload_lds16(const void* g, void* l) {
    __builtin_amdgcn_global_load_lds((const __attribute__((address_space(1))) void*)g,
                                     (__attribute__((address_space(3))) void*)l,
                                     16, 0, 0);
}

// ---------------- fp32 -> bf16 convert (vectorized), n multiple of 4
__global__ __launch_bounds__(256) void k_f2b(const float* __restrict__ src,
                                             unsigned short* __restrict__ dst, int n)
{
    int i = (blockIdx.x * 256 + threadIdx.x) * 4;
    if (i < n) {
        float4 v = *(const float4*)(src + i);
        unsigned short o0 = f2b(v.x), o1 = f2b(v.y), o2 = f2b(v.z), o3 = f2b(v.w);
        unsigned long long pack = (unsigned long long)o0 | ((unsigned long long)o1 << 16)
                                | ((unsigned long long)o2 << 32) | ((unsigned long long)o3 << 48);
        *(unsigned long long*)(dst + i) = pack;
    }
}

// ---------------- prep: cf[j] = sigmoid(vs_p) . vq_w[j] + vq_b[j]
__global__ __launch_bounds__(256) void k_cf(const float* __restrict__ vs_p,
                                            const float* __restrict__ vq_w,
                                            const float* __restrict__ vq_b,
                                            float* __restrict__ cf)
{
    const int wave = threadIdx.x >> 6, lane = threadIdx.x & 63;
    const int j = blockIdx.x * 4 + wave;
    const float* w = vq_w + (size_t)j * NHID;
    float p = 0.f;
    for (int i = lane; i < NHID; i += 64) p += sigf(vs_p[i]) * w[i];
#pragma unroll
    for (int off = 32; off; off >>= 1) p += __shfl_down(p, off);
    if (lane == 0) cf[j] = p + vq_b[j];
}

// sk carries 0.125 (1/sqrt(dim)) and log2(e): softmax done in base-2 domain.
__global__ __launch_bounds__(256) void k_scales(const float* __restrict__ qs_p,
                                                const float* __restrict__ ks_p,
                                                const float* __restrict__ r_gate,
                                                const float* __restrict__ cf,
                                                float* __restrict__ sq, float* __restrict__ sk,
                                                float* __restrict__ sv, float* __restrict__ rg)
{
    for (int n = threadIdx.x; n < NHID; n += 256) {
        sq[n] = sigf(qs_p[n]);
        sk[n] = sigf(ks_p[n]) * (0.125f * LOG2E);
        rg[n] = sigf(r_gate[n]);
        sv[n] = sigf(cf[n + NHID]) * tanhf(cf[n]);
    }
}

// ---------------- bf16 MFMA GEMM, 128x128 tile, BK=32, m97-style staging.
// A: [M][K] bf16 row-major.  B: [N][K] bf16 row-major (i.e. B^T layout).
// MODE 0: proj-> Qc right half (col 1024+n) AND Qa[bh][s][d]
// MODE 1: proj-> K [b*16+h][s][d] bf16
// MODE 3: proj-> V^T [b*16+h][d][s] bf16
// MODE 2: final: out fp32[m][n] = scale[n]*b2f(mixb[m*2048+n]) + gelu(acc+bias[n])
// Grid is always (64, 8) = 512 blocks; bijective XCD swizzle for L2 locality.
template<int MODE>
__global__ __launch_bounds__(256) void k_gemm(const unsigned short* __restrict__ A,
                                              const unsigned short* __restrict__ B,
                                              const float* __restrict__ bias,
                                              const float* __restrict__ scale,
                                              unsigned short* __restrict__ outb,
                                              unsigned short* __restrict__ outb2,
                                              float* __restrict__ outf,
                                              const unsigned short* __restrict__ mixb,
                                              int K)
{
    __shared__ unsigned short As[128 * 32];
    __shared__ unsigned short Bs[128 * 32];
    const int t = threadIdx.x;
    const int wid = t >> 6, lane = t & 63;
    const int wr = wid >> 1, wc = wid & 1;
    int wg = blockIdx.y * 64 + blockIdx.x;
    wg = (wg & 7) * 64 + (wg >> 3);          // 8 XCDs x 64 contiguous blocks
    const int bm = wg & 63, bn = wg >> 6;
    const unsigned short* Ab = A + (size_t)bm * 128 * K;
    const unsigned short* Bb = B + (size_t)bn * 128 * K;

    f32x4 acc[4][4] = {};

    const int srow = t >> 2;            // 0..63
    const int scol = (t & 3) * 8;       // ushort col within BK
    for (int k0 = 0; k0 < K; k0 += 32) {
        __syncthreads();
        gload_lds16(Ab + (size_t)srow * K + k0 + scol,        (char*)As + t * 16);
        gload_lds16(Ab + (size_t)(srow + 64) * K + k0 + scol, (char*)As + 4096 + t * 16);
        gload_lds16(Bb + (size_t)srow * K + k0 + scol,        (char*)Bs + t * 16);
        gload_lds16(Bb + (size_t)(srow + 64) * K + k0 + scol, (char*)Bs + 4096 + t * 16);
        __syncthreads();
        bf16x8 af[4], bf[4];
#pragma unroll
        for (int mi = 0; mi < 4; ++mi)
            af[mi] = *(const bf16x8*)&As[(wr * 64 + mi * 16 + (lane & 15)) * 32 + (lane >> 4) * 8];
#pragma unroll
        for (int ni = 0; ni < 4; ++ni)
            bf[ni] = *(const bf16x8*)&Bs[(wc * 64 + ni * 16 + (lane & 15)) * 32 + (lane >> 4) * 8];
#pragma unroll
        for (int mi = 0; mi < 4; ++mi)
#pragma unroll
            for (int ni = 0; ni < 4; ++ni)
                acc[mi][ni] = __builtin_amdgcn_mfma_f32_16x16x32_bf16(af[mi], bf[ni], acc[mi][ni], 0, 0, 0);
    }

#pragma unroll
    for (int mi = 0; mi < 4; ++mi) {
#pragma unroll
        for (int r = 0; r < 4; ++r) {
            const int m = bm * 128 + wr * 64 + mi * 16 + (lane >> 4) * 4 + r;
#pragma unroll
            for (int ni = 0; ni < 4; ++ni) {
                const int n = bn * 128 + wc * 64 + ni * 16 + (lane & 15);
                const float a = acc[mi][ni][r];
                if constexpr (MODE == 0) {
                    const float v = scale[n] * (a + bias[n]);
                    const int s = m >> 2, b = m & 3, h = n >> 6, d = n & 63;
                    outb[(size_t)m * 2048 + 1024 + n] = f2b(v);
                    outb2[((size_t)(b * HEADS + h) * SEQ + s) * DIM + d] = f2b(v);
                } else if constexpr (MODE == 1) {
                    const float v = scale[n] * (a + bias[n]);
                    const int s = m >> 2, b = m & 3, h = n >> 6, d = n & 63;
                    outb[((size_t)(b * HEADS + h) * SEQ + s) * DIM + d] = f2b(v);
                } else if constexpr (MODE == 3) {
                    const float v = scale[n] * (a + bias[n]);
                    const int s = m >> 2, b = m & 3, h = n >> 6, d = n & 63;
                    outb[((size_t)(b * HEADS + h) * DIM + d) * SEQ + s] = f2b(v);
                } else {
                    const float pre = a + bias[n];
                    const float g = pre * sigf(1.702f * pre);
                    const float mx = b2f(mixb[(size_t)m * 2048 + n]);
                    outf[(size_t)m * NHID + n] = scale[n] * mx + g;
                }
            }
        }
    }
}

// ---------------- MFMA flash attention, swapped-operand 32x32 structure.
// grid (SEQ/128, BATCH*HEADS), 256 thr = 4 waves x 32 q-rows.
// Qa: [bh][s][d], Kb: [bh][s][d], Vt: [bh][d][s]  (K pre-scaled by 0.125*log2e).
// mix written as bf16 into Qc[8192][2048] cols 0..1023.
//
// LDS tiles are [64 rows][8 chunks of 8 bf16] with T2 chunk-XOR swizzle
// (chunk' = chunk ^ (row&7)); staged via global_load_lds with pre-swizzled
// global source + linear LDS dest (rule 21). All b128 fragment reads are
// conflict-free. K/V double-buffered, 2-phase pipeline (T3 minimum).
#define LDS8(BASE, ROW, C8) \
    (*(const bf16x8*)&(BASE)[((ROW) << 6) + ((((C8) ^ ((ROW) & 7))) << 3)])

#define STAGE(KB, VB, J0) do {                                                   \
    _Pragma("unroll")                                                            \
    for (int it_ = 0; it_ < 2; ++it_) {                                          \
        const int ch_  = it_ * 256 + t;                                          \
        const int row_ = ch_ >> 3;                                               \
        const int c8_  = (ch_ & 7) ^ (row_ & 7);                                 \
        gload_lds16(Kbh + (size_t)((J0) + row_) * DIM + c8_ * 8,                 \
                    (char*)(KB) + ch_ * 16);                                     \
        gload_lds16(Vbh + (size_t)row_ * SEQ + (J0) + c8_ * 8,                   \
                    (char*)(VB) + ch_ * 16);                                     \
    }                                                                            \
} while (0)

#define TILE(KB, VB) do {                                                        \
    f32x16 sA = {}, sB = {};                                                     \
    _Pragma("unroll")                                                            \
    for (int ds_ = 0; ds_ < 4; ++ds_) {                                          \
        bf16x8 kf0 = LDS8(KB, q31,      ds_ * 2 + g2);                           \
        bf16x8 kf1 = LDS8(KB, 32 + q31, ds_ * 2 + g2);                           \
        sA = __builtin_amdgcn_mfma_f32_32x32x16_bf16(kf0, qf[ds_], sA, 0, 0, 0); \
        sB = __builtin_amdgcn_mfma_f32_32x32x16_bf16(kf1, qf[ds_], sB, 0, 0, 0); \
    }                                                                            \
    float mt = fmaxf(sA[0], sB[0]);                                              \
    _Pragma("unroll")                                                            \
    for (int i = 1; i < 16; ++i) mt = fmaxf(mt, fmaxf(sA[i], sB[i]));            \
    mt = fmaxf(mt, __shfl_xor(mt, 32));                                          \
    if (!__all(mt - m_r <= 8.0f)) {                                              \
        const float mn   = fmaxf(m_r, mt);                                       \
        const float corr = exp2f(m_r - mn);                                      \
        m_r = mn; l_r *= corr;                                                   \
        accO0 = accO0 * corr; accO1 = accO1 * corr;                              \
    }                                                                            \
    float psum = 0.f;                                                            \
    _Pragma("unroll")                                                            \
    for (int p = 0; p < 8; ++p) {                                                \
        const float p0 = exp2f(sA[2 * p] - m_r);                                 \
        const float p1 = exp2f(sA[2 * p + 1] - m_r);                             \
        psum += p0 + p1;                                                         \
        *(unsigned*)&Pwb[(q31 << 6) + ((((p >> 1) ^ (q31 & 7))) << 3)            \
                         + (2 * p & 3) + 4 * g2] = pk2(p0, p1);                  \
    }                                                                            \
    _Pragma("unroll")                                                            \
    for (int p = 0; p < 8; ++p) {                                                \
        const float p0 = exp2f(sB[2 * p] - m_r);                                 \
        const float p1 = exp2f(sB[2 * p + 1] - m_r);                             \
        psum += p0 + p1;                                                         \
        *(unsigned*)&Pwb[(q31 << 6) + (((((p >> 1) + 4) ^ (q31 & 7))) << 3)      \
                         + (2 * p & 3) + 4 * g2] = pk2(p0, p1);                  \
    }                                                                            \
    psum += __shfl_xor(psum, 32);                                                \
    l_r += psum;                                                                 \
    _Pragma("unroll")                                                            \
    for (int kc = 0; kc < 4; ++kc) {                                             \
        bf16x8 pf  = LDS8(Pwb, q31,      kc * 2 + g2);                           \
        bf16x8 vf0 = LDS8(VB,  q31,      kc * 2 + g2);                           \
        bf16x8 vf1 = LDS8(VB,  32 + q31, kc * 2 + g2);                           \
        accO0 = __builtin_amdgcn_mfma_f32_32x32x16_bf16(vf0, pf, accO0, 0, 0, 0);\
        accO1 = __builtin_amdgcn_mfma_f32_32x32x16_bf16(vf1, pf, accO1, 0, 0, 0);\
    }                                                                            \
} while (0)

__global__ __launch_bounds__(256) void k_attn(const unsigned short* __restrict__ Qa,
                                              const unsigned short* __restrict__ Kb,
                                              const unsigned short* __restrict__ Vt,
                                              unsigned short* __restrict__ mixo)
{
    __shared__ unsigned short Ks0[4096], Ks1[4096];   // K[j][d], swizzled chunks
    __shared__ unsigned short Vs0[4096], Vs1[4096];   // V^T[d][j], swizzled
    __shared__ unsigned short Pw[4][2048];            // per-wave P[q][j], swizzled
    const int t = threadIdx.x, wid = t >> 6, l = t & 63;
    const int g2 = l >> 5, q31 = l & 31;
    const int bh = blockIdx.y, b = bh >> 4, h = bh & 15;
    const int s_q = blockIdx.x * 128 + wid * 32 + q31;   // this lane's q row
    unsigned short* Pwb = &Pw[wid][0];

    const unsigned short* Kbh = Kb + (size_t)bh * SEQ * DIM;
    const unsigned short* Vbh = Vt + (size_t)bh * DIM * SEQ;
    const unsigned short* Qbh = Qa + (size_t)bh * SEQ * DIM;

    bf16x8 qf[4];
#pragma unroll
    for (int ds_ = 0; ds_ < 4; ++ds_)
        qf[ds_] = *(const bf16x8*)&Qbh[(size_t)s_q * DIM + ds_ * 16 + g2 * 8];

    f32x16 accO0 = {}, accO1 = {};             // d rows 0..31 / 32..63
    float m_r = -1e30f, l_r = 0.f;

    STAGE(Ks0, Vs0, 0);
#pragma unroll 1
    for (int j0 = 0; j0 < SEQ; j0 += 128) {
        __syncthreads();                       // buf0 loads done; buf1 free
        if (j0 + 64 < SEQ) STAGE(Ks1, Vs1, j0 + 64);
        TILE(Ks0, Vs0);
        __syncthreads();                       // buf1 loads done; buf0 free
        if (j0 + 128 < SEQ) STAGE(Ks0, Vs0, j0 + 128);
        TILE(Ks1, Vs1);
    }

    // ---- epilogue: mix[q][d] = accO^T / l   (C/D: col=q31, row=d)
    const float inv = 1.f / l_r;
    unsigned short* dst = mixo + (size_t)(s_q * 4 + b) * 2048 + h * 64;
#pragma unroll
    for (int reg = 0; reg < 16; reg += 2) {
        const int d0a = (reg & 3) + 8 * (reg >> 2) + 4 * g2;
        *(unsigned*)&dst[d0a]      = pk2(accO0[reg] * inv, accO0[reg + 1] * inv);
        *(unsigned*)&dst[32 + d0a] = pk2(accO1[reg] * inv, accO1[reg + 1] * inv);
    }
}

extern "C" void kernel_launch(void* const* d_in, const int* in_sizes, int n_in,
                              void* d_out, int out_size, void* d_ws, size_t ws_size,
                              hipStream_t stream)
{
    (void)in_sizes; (void)n_in; (void)out_size; (void)ws_size;
    const float* query  = (const float*)d_in[0];
    const float* key    = (const float*)d_in[1];
    const float* value  = (const float*)d_in[2];
    const float* qs_p   = (const float*)d_in[3];
    const float* ks_p   = (const float*)d_in[4];
    const float* vs_p   = (const float*)d_in[5];
    const float* vq_w   = (const float*)d_in[6];
    const float* vq_b   = (const float*)d_in[7];
    const float* q_w    = (const float*)d_in[8];
    const float* q_b    = (const float*)d_in[9];
    const float* k_w    = (const float*)d_in[10];
    const float* k_b    = (const float*)d_in[11];
    const float* v_w    = (const float*)d_in[12];
    const float* v_b    = (const float*)d_in[13];
    const float* r_w    = (const float*)d_in[14];
    const float* r_b    = (const float*)d_in[15];
    const float* r_gate = (const float*)d_in[16];

    float* fws = (float*)d_ws;
    float* sq = fws;
    float* sk = fws + 1024;
    float* sv = fws + 2048;
    float* rg = fws + 3072;
    float* cf = fws + 4096;                 // 2048 floats

    unsigned short* uws = (unsigned short*)(fws + 8192);
    unsigned short* Xq = uws;                                   // 8192*1024
    unsigned short* Xk = Xq + (size_t)MROWS * NHID;
    unsigned short* Xv = Xk + (size_t)MROWS * NHID;
    unsigned short* Wq = Xv + (size_t)MROWS * NHID;             // 1024*1024
    unsigned short* Wk = Wq + (size_t)NHID * NHID;
    unsigned short* Wv = Wk + (size_t)NHID * NHID;
    unsigned short* Wr = Wv + (size_t)NHID * NHID;              // 1024*2048
    unsigned short* Qc = Wr + (size_t)NHID * 2 * NHID;          // 8192*2048
    unsigned short* Kb = Qc + (size_t)MROWS * 2 * NHID;         // 64*2048*64
    unsigned short* Vb = Kb + (size_t)BATCH * HEADS * SEQ * DIM;
    unsigned short* Qa = Xk;   // aliases Xk (dead after K-projection)

    k_cf<<<dim3(512), dim3(256), 0, stream>>>(vs_p, vq_w, vq_b, cf);
    k_scales<<<dim3(1), dim3(256), 0, stream>>>(qs_p, ks_p, r_gate, cf, sq, sk, sv, rg);

    const int NIN = MROWS * NHID;           // 8388608
    k_f2b<<<dim3(NIN / 1024), dim3(256), 0, stream>>>(query, Xq, NIN);
    k_f2b<<<dim3(NIN / 1024), dim3(256), 0, stream>>>(key,   Xk, NIN);
    k_f2b<<<dim3(NIN / 1024), dim3(256), 0, stream>>>(value, Xv, NIN);
    k_f2b<<<dim3(1024), dim3(256), 0, stream>>>(q_w, Wq, NHID * NHID);
    k_f2b<<<dim3(1024), dim3(256), 0, stream>>>(k_w, Wk, NHID * NHID);
    k_f2b<<<dim3(1024), dim3(256), 0, stream>>>(v_w, Wv, NHID * NHID);
    k_f2b<<<dim3(2048), dim3(256), 0, stream>>>(r_w, Wr, NHID * 2 * NHID);

    // K and V projections first (they consume Xk/Xv); Q last, writing Qa over Xk.
    k_gemm<1><<<dim3(64, 8), dim3(256), 0, stream>>>(Xk, Wk, k_b, sk, Kb, nullptr, nullptr, nullptr, NHID);
    k_gemm<3><<<dim3(64, 8), dim3(256), 0, stream>>>(Xv, Wv, v_b, sv, Vb, nullptr, nullptr, nullptr, NHID);
    k_gemm<0><<<dim3(64, 8), dim3(256), 0, stream>>>(Xq, Wq, q_b, sq, Qc, Qa, nullptr, nullptr, NHID);

    k_attn<<<dim3(SEQ / 128, BATCH * HEADS), dim3(256), 0, stream>>>(Qa, Kb, Vb, Qc);

    k_gemm<2><<<dim3(64, 8), dim3(256), 0, stream>>>(Qc, Wr, r_b, rg, nullptr, nullptr, (float*)d_out, Qc, 2 * NHID);
}

// Round 7
// 361.947 us; speedup vs baseline: 8.8073x; 1.0204x over previous
//
#include <hip/hip_runtime.h>
#include <hip/hip_bf16.h>
#include <math.h>

#define SEQ   2048
#define BATCH 4
#define NHID  1024
#define HEADS 16
#define DIM   64
#define MROWS (SEQ*BATCH)   // 8192
#define LOG2E 1.44269504f

typedef __attribute__((ext_vector_type(8)))  short bf16x8;
typedef __attribute__((ext_vector_type(4)))  float f32x4;
typedef __attribute__((ext_vector_type(16))) float f32x16;

__device__ __forceinline__ float sigf(float x) { return 1.0f / (1.0f + expf(-x)); }

__device__ __forceinline__ unsigned short f2b(float x) {
    unsigned int u = __float_as_uint(x);
    return (unsigned short)((u + 0x7FFFu + ((u >> 16) & 1u)) >> 16);
}
__device__ __forceinline__ float b2f(unsigned short h) {
    return __uint_as_float(((unsigned int)h) << 16);
}
__device__ __forceinline__ unsigned pk2(float lo, float hi) {
    __hip_bfloat162 h = __float22bfloat162_rn(make_float2(lo, hi));
    union { __hip_bfloat162 h; unsigned u; } cv; cv.h = h;
    return cv.u;
}
__device__ __forceinline__ void gload_lds16(const void* g, void* l) {
    __builtin_amdgcn_global_load_lds((const __attribute__((address_space(1))) void*)g,
                                     (__attribute__((address_space(3))) void*)l,
                                     16, 0, 0);
}

// ---------------- fused fp32 -> bf16 convert for all 7 tensors
// segment block ranges: X q/k/v: 8192 each; Wq/Wk/Wv: 1024 each; Wr: 2048.
__global__ __launch_bounds__(256) void k_f2b_all(const float* __restrict__ s0,
                                                 const float* __restrict__ s1,
                                                 const float* __restrict__ s2,
                                                 const float* __restrict__ s3,
                                                 const float* __restrict__ s4,
                                                 const float* __restrict__ s5,
                                                 const float* __restrict__ s6,
                                                 unsigned short* __restrict__ d0,
                                                 unsigned short* __restrict__ d1,
                                                 unsigned short* __restrict__ d2,
                                                 unsigned short* __restrict__ d3,
                                                 unsigned short* __restrict__ d4,
                                                 unsigned short* __restrict__ d5,
                                                 unsigned short* __restrict__ d6)
{
    int blk = blockIdx.x;
    const float* src; unsigned short* dst;
    if      (blk < 8192)  { src = s0; dst = d0; }
    else if (blk < 16384) { src = s1; dst = d1; blk -= 8192;  }
    else if (blk < 24576) { src = s2; dst = d2; blk -= 16384; }
    else if (blk < 25600) { src = s3; dst = d3; blk -= 24576; }
    else if (blk < 26624) { src = s4; dst = d4; blk -= 25600; }
    else if (blk < 27648) { src = s5; dst = d5; blk -= 26624; }
    else                  { src = s6; dst = d6; blk -= 27648; }
    const int i = (blk * 256 + threadIdx.x) * 4;
    float4 v = *(const float4*)(src + i);
    unsigned long long pack = (unsigned long long)f2b(v.x)
                            | ((unsigned long long)f2b(v.y) << 16)
                            | ((unsigned long long)f2b(v.z) << 32)
                            | ((unsigned long long)f2b(v.w) << 48);
    *(unsigned long long*)(dst + i) = pack;
}

// ---------------- prep: cf[j] = sigmoid(vs_p) . vq_w[j] + vq_b[j]
__global__ __launch_bounds__(256) void k_cf(const float* __restrict__ vs_p,
                                            const float* __restrict__ vq_w,
                                            const float* __restrict__ vq_b,
                                            float* __restrict__ cf)
{
    const int wave = threadIdx.x >> 6, lane = threadIdx.x & 63;
    const int j = blockIdx.x * 4 + wave;
    const float* w = vq_w + (size_t)j * NHID;
    float p = 0.f;
    for (int i = lane; i < NHID; i += 64) p += sigf(vs_p[i]) * w[i];
#pragma unroll
    for (int off = 32; off; off >>= 1) p += __shfl_down(p, off);
    if (lane == 0) cf[j] = p + vq_b[j];
}

// sk carries 0.125 (1/sqrt(dim)) and log2(e): softmax done in base-2 domain.
__global__ __launch_bounds__(256) void k_scales(const float* __restrict__ qs_p,
                                                const float* __restrict__ ks_p,
                                                const float* __restrict__ r_gate,
                                                const float* __restrict__ cf,
                                                float* __restrict__ sq, float* __restrict__ sk,
                                                float* __restrict__ sv, float* __restrict__ rg)
{
    for (int n = threadIdx.x; n < NHID; n += 256) {
        sq[n] = sigf(qs_p[n]);
        sk[n] = sigf(ks_p[n]) * (0.125f * LOG2E);
        rg[n] = sigf(r_gate[n]);
        sv[n] = sigf(cf[n + NHID]) * tanhf(cf[n]);
    }
}

// ---------------- bf16 MFMA GEMM, 128x128 tile, BK=32, m97-style staging.
// A: [M][K] bf16 row-major.  B: [N][K] bf16 row-major (i.e. B^T layout).
// MODE 0: proj-> Qc right half (col 1024+n)
// MODE 1: proj-> K [b*16+h][s][d] bf16
// MODE 3: proj-> V^T [b*16+h][d][s] bf16
// MODE 2: final: out fp32[m][n] = scale[n]*b2f(mixb[m*2048+n]) + gelu(acc+bias[n])
// Grid is always (64, 8) = 512 blocks; bijective XCD swizzle for L2 locality.
template<int MODE>
__global__ __launch_bounds__(256) void k_gemm(const unsigned short* __restrict__ A,
                                              const unsigned short* __restrict__ B,
                                              const float* __restrict__ bias,
                                              const float* __restrict__ scale,
                                              unsigned short* __restrict__ outb,
                                              float* __restrict__ outf,
                                              const unsigned short* __restrict__ mixb,
                                              int K)
{
    __shared__ unsigned short As[128 * 32];
    __shared__ unsigned short Bs[128 * 32];
    const int t = threadIdx.x;
    const int wid = t >> 6, lane = t & 63;
    const int wr = wid >> 1, wc = wid & 1;
    int wg = blockIdx.y * 64 + blockIdx.x;
    wg = (wg & 7) * 64 + (wg >> 3);          // 8 XCDs x 64 contiguous blocks
    const int bm = wg & 63, bn = wg >> 6;
    const unsigned short* Ab = A + (size_t)bm * 128 * K;
    const unsigned short* Bb = B + (size_t)bn * 128 * K;

    f32x4 acc[4][4] = {};

    const int srow = t >> 2;            // 0..63
    const int scol = (t & 3) * 8;       // ushort col within BK
    for (int k0 = 0; k0 < K; k0 += 32) {
        __syncthreads();
        gload_lds16(Ab + (size_t)srow * K + k0 + scol,        (char*)As + t * 16);
        gload_lds16(Ab + (size_t)(srow + 64) * K + k0 + scol, (char*)As + 4096 + t * 16);
        gload_lds16(Bb + (size_t)srow * K + k0 + scol,        (char*)Bs + t * 16);
        gload_lds16(Bb + (size_t)(srow + 64) * K + k0 + scol, (char*)Bs + 4096 + t * 16);
        __syncthreads();
        bf16x8 af[4], bf[4];
#pragma unroll
        for (int mi = 0; mi < 4; ++mi)
            af[mi] = *(const bf16x8*)&As[(wr * 64 + mi * 16 + (lane & 15)) * 32 + (lane >> 4) * 8];
#pragma unroll
        for (int ni = 0; ni < 4; ++ni)
            bf[ni] = *(const bf16x8*)&Bs[(wc * 64 + ni * 16 + (lane & 15)) * 32 + (lane >> 4) * 8];
#pragma unroll
        for (int mi = 0; mi < 4; ++mi)
#pragma unroll
            for (int ni = 0; ni < 4; ++ni)
                acc[mi][ni] = __builtin_amdgcn_mfma_f32_16x16x32_bf16(af[mi], bf[ni], acc[mi][ni], 0, 0, 0);
    }

#pragma unroll
    for (int mi = 0; mi < 4; ++mi) {
#pragma unroll
        for (int r = 0; r < 4; ++r) {
            const int m = bm * 128 + wr * 64 + mi * 16 + (lane >> 4) * 4 + r;
#pragma unroll
            for (int ni = 0; ni < 4; ++ni) {
                const int n = bn * 128 + wc * 64 + ni * 16 + (lane & 15);
                const float a = acc[mi][ni][r];
                if constexpr (MODE == 0) {
                    const float v = scale[n] * (a + bias[n]);
                    outb[(size_t)m * 2048 + 1024 + n] = f2b(v);
                } else if constexpr (MODE == 1) {
                    const float v = scale[n] * (a + bias[n]);
                    const int s = m >> 2, b = m & 3, h = n >> 6, d = n & 63;
                    outb[((size_t)(b * HEADS + h) * SEQ + s) * DIM + d] = f2b(v);
                } else if constexpr (MODE == 3) {
                    const float v = scale[n] * (a + bias[n]);
                    const int s = m >> 2, b = m & 3, h = n >> 6, d = n & 63;
                    outb[((size_t)(b * HEADS + h) * DIM + d) * SEQ + s] = f2b(v);
                } else {
                    const float pre = a + bias[n];
                    const float g = pre * sigf(1.702f * pre);
                    const float mx = b2f(mixb[(size_t)m * 2048 + n]);
                    outf[(size_t)m * NHID + n] = scale[n] * mx + g;
                }
            }
        }
    }
}

// ---------------- MFMA flash attention, swapped-operand 32x32 structure.
// grid (SEQ/128, BATCH*HEADS), 256 thr = 4 waves x 32 q-rows.
// Q read from Qc[8192][2048] cols 1024..2047; Kb: [bh][s][d], Vt: [bh][d][s]
// (K pre-scaled by 0.125*log2e). mix written to Qc cols 0..1023 (disjoint).
//
// K/V LDS tiles are [64 rows][8 chunks of 8 bf16], chunk-XOR swizzled,
// staged via global_load_lds with pre-swizzled source (rule 21), dbuf'd.
// P never touches LDS: PV's B-fragment for j-chunk kc is ppk[4(kc&1)+8(kc>>1)
// .. +3] — own half-wave supplies 2 words, the lane^32 peer (via
// __shfl_xor(·,32)) supplies the other 2. Derived from the C/D layout
// (row=(reg&3)+8*(reg>>2)+4*g2) and B layout (k=(l>>5)*8+e), both verified
// by this kernel's own passing QK^T/epilogue.
#define LDS8(BASE, ROW, C8) \
    (*(const bf16x8*)&(BASE)[((ROW) << 6) + ((((C8) ^ ((ROW) & 7))) << 3)])

#define STAGE(KB, VB, J0) do {                                                   \
    _Pragma("unroll")                                                            \
    for (int it_ = 0; it_ < 2; ++it_) {                                          \
        const int ch_  = it_ * 256 + t;                                          \
        const int row_ = ch_ >> 3;                                               \
        const int c8_  = (ch_ & 7) ^ (row_ & 7);                                 \
        gload_lds16(Kbh + (size_t)((J0) + row_) * DIM + c8_ * 8,                 \
                    (char*)(KB) + ch_ * 16);                                     \
        gload_lds16(Vbh + (size_t)row_ * SEQ + (J0) + c8_ * 8,                   \
                    (char*)(VB) + ch_ * 16);                                     \
    }                                                                            \
} while (0)

#define TILE(KB, VB) do {                                                        \
    f32x16 sA = {}, sB = {};                                                     \
    _Pragma("unroll")                                                            \
    for (int ds_ = 0; ds_ < 4; ++ds_) {                                          \
        bf16x8 kf0 = LDS8(KB, q31,      ds_ * 2 + g2);                           \
        bf16x8 kf1 = LDS8(KB, 32 + q31, ds_ * 2 + g2);                           \
        sA = __builtin_amdgcn_mfma_f32_32x32x16_bf16(kf0, qf[ds_], sA, 0, 0, 0); \
        sB = __builtin_amdgcn_mfma_f32_32x32x16_bf16(kf1, qf[ds_], sB, 0, 0, 0); \
    }                                                                            \
    float tm[8];                                                                 \
    _Pragma("unroll")                                                            \
    for (int i = 0; i < 8; ++i)                                                  \
        tm[i] = fmaxf(fmaxf(sA[2 * i], sA[2 * i + 1]),                           \
                      fmaxf(sB[2 * i], sB[2 * i + 1]));                          \
    _Pragma("unroll")                                                            \
    for (int i = 0; i < 4; ++i) tm[i] = fmaxf(tm[i], tm[i + 4]);                 \
    float mt = fmaxf(fmaxf(tm[0], tm[1]), fmaxf(tm[2], tm[3]));                  \
    mt = fmaxf(mt, __shfl_xor(mt, 32));                                          \
    if (!__all(mt - m_r <= 8.0f)) {                                              \
        const float mn   = fmaxf(m_r, mt);                                       \
        const float corr = exp2f(m_r - mn);                                      \
        m_r = mn; l_r *= corr;                                                   \
        accO0 = accO0 * corr; accO1 = accO1 * corr;                              \
    }                                                                            \
    float ps0 = 0.f, ps1 = 0.f, ps2 = 0.f, ps3 = 0.f;                            \
    unsigned ppk[16];                                                            \
    _Pragma("unroll")                                                            \
    for (int p = 0; p < 8; ++p) {                                                \
        const float a0 = exp2f(sA[2 * p] - m_r);                                 \
        const float a1 = exp2f(sA[2 * p + 1] - m_r);                             \
        const float b0 = exp2f(sB[2 * p] - m_r);                                 \
        const float b1 = exp2f(sB[2 * p + 1] - m_r);                             \
        ps0 += a0; ps1 += a1; ps2 += b0; ps3 += b1;                              \
        ppk[p]     = pk2(a0, a1);                                                \
        ppk[8 + p] = pk2(b0, b1);                                                \
    }                                                                            \
    float psum = (ps0 + ps1) + (ps2 + ps3);                                      \
    psum += __shfl_xor(psum, 32);                                                \
    l_r += psum;                                                                 \
    _Pragma("unroll")                                                            \
    for (int kc = 0; kc < 4; ++kc) {                                             \
        const int i0 = 4 * (kc & 1) + 8 * (kc >> 1);                             \
        const unsigned sh0 = __shfl_xor(ppk[i0],     32);                        \
        const unsigned sh1 = __shfl_xor(ppk[i0 + 1], 32);                        \
        const unsigned sh2 = __shfl_xor(ppk[i0 + 2], 32);                        \
        const unsigned sh3 = __shfl_xor(ppk[i0 + 3], 32);                        \
        union { unsigned w[4]; bf16x8 v; } up;                                   \
        up.w[0] = g2 ? sh2 : ppk[i0];                                            \
        up.w[1] = g2 ? sh3 : ppk[i0 + 1];                                        \
        up.w[2] = g2 ? ppk[i0 + 2] : sh0;                                        \
        up.w[3] = g2 ? ppk[i0 + 3] : sh1;                                        \
        bf16x8 vf0 = LDS8(VB, q31,      kc * 2 + g2);                            \
        bf16x8 vf1 = LDS8(VB, 32 + q31, kc * 2 + g2);                            \
        accO0 = __builtin_amdgcn_mfma_f32_32x32x16_bf16(vf0, up.v, accO0, 0, 0, 0);\
        accO1 = __builtin_amdgcn_mfma_f32_32x32x16_bf16(vf1, up.v, accO1, 0, 0, 0);\
    }                                                                            \
} while (0)

__global__ __launch_bounds__(256) void k_attn(const unsigned short* __restrict__ Qc,
                                              const unsigned short* __restrict__ Kb,
                                              const unsigned short* __restrict__ Vt,
                                              unsigned short* __restrict__ mixo)
{
    __shared__ unsigned short Ks0[4096], Ks1[4096];   // K[j][d], swizzled chunks
    __shared__ unsigned short Vs0[4096], Vs1[4096];   // V^T[d][j], swizzled
    const int t = threadIdx.x, wid = t >> 6, l = t & 63;
    const int g2 = l >> 5, q31 = l & 31;
    const int bh = blockIdx.y, b = bh >> 4, h = bh & 15;
    const int s_q = blockIdx.x * 128 + wid * 32 + q31;   // this lane's q row

    const unsigned short* Kbh = Kb + (size_t)bh * SEQ * DIM;
    const unsigned short* Vbh = Vt + (size_t)bh * DIM * SEQ;
    const unsigned short* Qrow = Qc + (size_t)(s_q * 4 + b) * 2048 + 1024 + h * 64;

    bf16x8 qf[4];
#pragma unroll
    for (int ds_ = 0; ds_ < 4; ++ds_)
        qf[ds_] = *(const bf16x8*)&Qrow[ds_ * 16 + g2 * 8];

    f32x16 accO0 = {}, accO1 = {};             // d rows 0..31 / 32..63
    float m_r = -1e30f, l_r = 0.f;

    STAGE(Ks0, Vs0, 0);
#pragma unroll 1
    for (int j0 = 0; j0 < SEQ; j0 += 128) {
        __syncthreads();                       // buf0 loads done; buf1 free
        if (j0 + 64 < SEQ) STAGE(Ks1, Vs1, j0 + 64);
        TILE(Ks0, Vs0);
        __syncthreads();                       // buf1 loads done; buf0 free
        if (j0 + 128 < SEQ) STAGE(Ks0, Vs0, j0 + 128);
        TILE(Ks1, Vs1);
    }

    // ---- epilogue: mix[q][d] = accO^T / l   (C/D: col=q31, row=d)
    const float inv = 1.f / l_r;
    unsigned short* dst = mixo + (size_t)(s_q * 4 + b) * 2048 + h * 64;
#pragma unroll
    for (int reg = 0; reg < 16; reg += 2) {
        const int d0a = (reg & 3) + 8 * (reg >> 2) + 4 * g2;
        *(unsigned*)&dst[d0a]      = pk2(accO0[reg] * inv, accO0[reg + 1] * inv);
        *(unsigned*)&dst[32 + d0a] = pk2(accO1[reg] * inv, accO1[reg + 1] * inv);
    }
}

extern "C" void kernel_launch(void* const* d_in, const int* in_sizes, int n_in,
                              void* d_out, int out_size, void* d_ws, size_t ws_size,
                              hipStream_t stream)
{
    (void)in_sizes; (void)n_in; (void)out_size; (void)ws_size;
    const float* query  = (const float*)d_in[0];
    const float* key    = (const float*)d_in[1];
    const float* value  = (const float*)d_in[2];
    const float* qs_p   = (const float*)d_in[3];
    const float* ks_p   = (const float*)d_in[4];
    const float* vs_p   = (const float*)d_in[5];
    const float* vq_w   = (const float*)d_in[6];
    const float* vq_b   = (const float*)d_in[7];
    const float* q_w    = (const float*)d_in[8];
    const float* q_b    = (const float*)d_in[9];
    const float* k_w    = (const float*)d_in[10];
    const float* k_b    = (const float*)d_in[11];
    const float* v_w    = (const float*)d_in[12];
    const float* v_b    = (const float*)d_in[13];
    const float* r_w    = (const float*)d_in[14];
    const float* r_b    = (const float*)d_in[15];
    const float* r_gate = (const float*)d_in[16];

    float* fws = (float*)d_ws;
    float* sq = fws;
    float* sk = fws + 1024;
    float* sv = fws + 2048;
    float* rg = fws + 3072;
    float* cf = fws + 4096;                 // 2048 floats

    unsigned short* uws = (unsigned short*)(fws + 8192);
    unsigned short* Xq = uws;                                   // 8192*1024
    unsigned short* Xk = Xq + (size_t)MROWS * NHID;
    unsigned short* Xv = Xk + (size_t)MROWS * NHID;
    unsigned short* Wq = Xv + (size_t)MROWS * NHID;             // 1024*1024
    unsigned short* Wk = Wq + (size_t)NHID * NHID;
    unsigned short* Wv = Wk + (size_t)NHID * NHID;
    unsigned short* Wr = Wv + (size_t)NHID * NHID;              // 1024*2048
    unsigned short* Qc = Wr + (size_t)NHID * 2 * NHID;          // 8192*2048
    unsigned short* Kb = Qc + (size_t)MROWS * 2 * NHID;         // 64*2048*64
    unsigned short* Vb = Kb + (size_t)BATCH * HEADS * SEQ * DIM;

    k_cf<<<dim3(512), dim3(256), 0, stream>>>(vs_p, vq_w, vq_b, cf);
    k_scales<<<dim3(1), dim3(256), 0, stream>>>(qs_p, ks_p, r_gate, cf, sq, sk, sv, rg);

    k_f2b_all<<<dim3(29696), dim3(256), 0, stream>>>(query, key, value,
                                                     q_w, k_w, v_w, r_w,
                                                     Xq, Xk, Xv, Wq, Wk, Wv, Wr);

    k_gemm<1><<<dim3(64, 8), dim3(256), 0, stream>>>(Xk, Wk, k_b, sk, Kb, nullptr, nullptr, NHID);
    k_gemm<3><<<dim3(64, 8), dim3(256), 0, stream>>>(Xv, Wv, v_b, sv, Vb, nullptr, nullptr, NHID);
    k_gemm<0><<<dim3(64, 8), dim3(256), 0, stream>>>(Xq, Wq, q_b, sq, Qc, nullptr, nullptr, NHID);

    k_attn<<<dim3(SEQ / 128, BATCH * HEADS), dim3(256), 0, stream>>>(Qc, Kb, Vb, Qc);

    k_gemm<2><<<dim3(64, 8), dim3(256), 0, stream>>>(Qc, Wr, r_b, rg, nullptr, (float*)d_out, Qc, 2 * NHID);
}

// Round 8
// 353.270 us; speedup vs baseline: 9.0237x; 1.0246x over previous
//
#include <hip/hip_runtime.h>
#include <hip/hip_bf16.h>
#include <math.h>

#define SEQ   2048
#define BATCH 4
#define NHID  1024
#define HEADS 16
#define DIM   64
#define MROWS (SEQ*BATCH)   // 8192
#define LOG2E 1.44269504f

typedef __attribute__((ext_vector_type(8)))  short bf16x8;
typedef __attribute__((ext_vector_type(4)))  float f32x4;
typedef __attribute__((ext_vector_type(16))) float f32x16;

__device__ __forceinline__ float sigf(float x) { return 1.0f / (1.0f + expf(-x)); }

__device__ __forceinline__ unsigned short f2b(float x) {
    unsigned int u = __float_as_uint(x);
    return (unsigned short)((u + 0x7FFFu + ((u >> 16) & 1u)) >> 16);
}
__device__ __forceinline__ float b2f(unsigned short h) {
    return __uint_as_float(((unsigned int)h) << 16);
}
__device__ __forceinline__ unsigned pk2(float lo, float hi) {
    __hip_bfloat162 h = __float22bfloat162_rn(make_float2(lo, hi));
    union { __hip_bfloat162 h; unsigned u; } cv; cv.h = h;
    return cv.u;
}
__device__ __forceinline__ void gload_lds16(const void* g, void* l) {
    __builtin_amdgcn_global_load_lds((const __attribute__((address_space(1))) void*)g,
                                     (__attribute__((address_space(3))) void*)l,
                                     16, 0, 0);
}

// ---------------- fused fp32 -> bf16 convert for all 7 tensors
__global__ __launch_bounds__(256) void k_f2b_all(const float* __restrict__ s0,
                                                 const float* __restrict__ s1,
                                                 const float* __restrict__ s2,
                                                 const float* __restrict__ s3,
                                                 const float* __restrict__ s4,
                                                 const float* __restrict__ s5,
                                                 const float* __restrict__ s6,
                                                 unsigned short* __restrict__ d0,
                                                 unsigned short* __restrict__ d1,
                                                 unsigned short* __restrict__ d2,
                                                 unsigned short* __restrict__ d3,
                                                 unsigned short* __restrict__ d4,
                                                 unsigned short* __restrict__ d5,
                                                 unsigned short* __restrict__ d6)
{
    int blk = blockIdx.x;
    const float* src; unsigned short* dst;
    if      (blk < 8192)  { src = s0; dst = d0; }
    else if (blk < 16384) { src = s1; dst = d1; blk -= 8192;  }
    else if (blk < 24576) { src = s2; dst = d2; blk -= 16384; }
    else if (blk < 25600) { src = s3; dst = d3; blk -= 24576; }
    else if (blk < 26624) { src = s4; dst = d4; blk -= 25600; }
    else if (blk < 27648) { src = s5; dst = d5; blk -= 26624; }
    else                  { src = s6; dst = d6; blk -= 27648; }
    const int i = (blk * 256 + threadIdx.x) * 4;
    float4 v = *(const float4*)(src + i);
    unsigned long long pack = (unsigned long long)f2b(v.x)
                            | ((unsigned long long)f2b(v.y) << 16)
                            | ((unsigned long long)f2b(v.z) << 32)
                            | ((unsigned long long)f2b(v.w) << 48);
    *(unsigned long long*)(dst + i) = pack;
}

// ---------------- prep: cf[j] = sigmoid(vs_p) . vq_w[j] + vq_b[j]
__global__ __launch_bounds__(256) void k_cf(const float* __restrict__ vs_p,
                                            const float* __restrict__ vq_w,
                                            const float* __restrict__ vq_b,
                                            float* __restrict__ cf)
{
    const int wave = threadIdx.x >> 6, lane = threadIdx.x & 63;
    const int j = blockIdx.x * 4 + wave;
    const float* w = vq_w + (size_t)j * NHID;
    float p = 0.f;
    for (int i = lane; i < NHID; i += 64) p += sigf(vs_p[i]) * w[i];
#pragma unroll
    for (int off = 32; off; off >>= 1) p += __shfl_down(p, off);
    if (lane == 0) cf[j] = p + vq_b[j];
}

// sk carries 0.125 (1/sqrt(dim)) and log2(e): softmax done in base-2 domain.
__global__ __launch_bounds__(256) void k_scales(const float* __restrict__ qs_p,
                                                const float* __restrict__ ks_p,
                                                const float* __restrict__ r_gate,
                                                const float* __restrict__ cf,
                                                float* __restrict__ sq, float* __restrict__ sk,
                                                float* __restrict__ sv, float* __restrict__ rg)
{
    for (int n = threadIdx.x; n < NHID; n += 256) {
        sq[n] = sigf(qs_p[n]);
        sk[n] = sigf(ks_p[n]) * (0.125f * LOG2E);
        rg[n] = sigf(r_gate[n]);
        sv[n] = sigf(cf[n + NHID]) * tanhf(cf[n]);
    }
}

// ---------------- bf16 MFMA GEMM, 128x128 tile, BK=32, m97-style staging.
// MODE 0: proj-> Qc right half (col 1024+n)
// MODE 1: proj-> K [b*16+h][s][d] bf16
// MODE 3: proj-> V^T [b*16+h][d][s] bf16
// MODE 2: final: out fp32[m][n] = scale[n]*b2f(mixb[m*2048+n]) + gelu(acc+bias[n])
template<int MODE>
__global__ __launch_bounds__(256) void k_gemm(const unsigned short* __restrict__ A,
                                              const unsigned short* __restrict__ B,
                                              const float* __restrict__ bias,
                                              const float* __restrict__ scale,
                                              unsigned short* __restrict__ outb,
                                              float* __restrict__ outf,
                                              const unsigned short* __restrict__ mixb,
                                              int K)
{
    __shared__ unsigned short As[128 * 32];
    __shared__ unsigned short Bs[128 * 32];
    const int t = threadIdx.x;
    const int wid = t >> 6, lane = t & 63;
    const int wr = wid >> 1, wc = wid & 1;
    int wg = blockIdx.y * 64 + blockIdx.x;
    wg = (wg & 7) * 64 + (wg >> 3);          // 8 XCDs x 64 contiguous blocks
    const int bm = wg & 63, bn = wg >> 6;
    const unsigned short* Ab = A + (size_t)bm * 128 * K;
    const unsigned short* Bb = B + (size_t)bn * 128 * K;

    f32x4 acc[4][4] = {};

    const int srow = t >> 2;            // 0..63
    const int scol = (t & 3) * 8;       // ushort col within BK
    for (int k0 = 0; k0 < K; k0 += 32) {
        __syncthreads();
        gload_lds16(Ab + (size_t)srow * K + k0 + scol,        (char*)As + t * 16);
        gload_lds16(Ab + (size_t)(srow + 64) * K + k0 + scol, (char*)As + 4096 + t * 16);
        gload_lds16(Bb + (size_t)srow * K + k0 + scol,        (char*)Bs + t * 16);
        gload_lds16(Bb + (size_t)(srow + 64) * K + k0 + scol, (char*)Bs + 4096 + t * 16);
        __syncthreads();
        bf16x8 af[4], bf[4];
#pragma unroll
        for (int mi = 0; mi < 4; ++mi)
            af[mi] = *(const bf16x8*)&As[(wr * 64 + mi * 16 + (lane & 15)) * 32 + (lane >> 4) * 8];
#pragma unroll
        for (int ni = 0; ni < 4; ++ni)
            bf[ni] = *(const bf16x8*)&Bs[(wc * 64 + ni * 16 + (lane & 15)) * 32 + (lane >> 4) * 8];
#pragma unroll
        for (int mi = 0; mi < 4; ++mi)
#pragma unroll
            for (int ni = 0; ni < 4; ++ni)
                acc[mi][ni] = __builtin_amdgcn_mfma_f32_16x16x32_bf16(af[mi], bf[ni], acc[mi][ni], 0, 0, 0);
    }

#pragma unroll
    for (int mi = 0; mi < 4; ++mi) {
#pragma unroll
        for (int r = 0; r < 4; ++r) {
            const int m = bm * 128 + wr * 64 + mi * 16 + (lane >> 4) * 4 + r;
#pragma unroll
            for (int ni = 0; ni < 4; ++ni) {
                const int n = bn * 128 + wc * 64 + ni * 16 + (lane & 15);
                const float a = acc[mi][ni][r];
                if constexpr (MODE == 0) {
                    const float v = scale[n] * (a + bias[n]);
                    outb[(size_t)m * 2048 + 1024 + n] = f2b(v);
                } else if constexpr (MODE == 1) {
                    const float v = scale[n] * (a + bias[n]);
                    const int s = m >> 2, b = m & 3, h = n >> 6, d = n & 63;
                    outb[((size_t)(b * HEADS + h) * SEQ + s) * DIM + d] = f2b(v);
                } else if constexpr (MODE == 3) {
                    const float v = scale[n] * (a + bias[n]);
                    const int s = m >> 2, b = m & 3, h = n >> 6, d = n & 63;
                    outb[((size_t)(b * HEADS + h) * DIM + d) * SEQ + s] = f2b(v);
                } else {
                    const float pre = a + bias[n];
                    const float g = pre * sigf(1.702f * pre);
                    const float mx = b2f(mixb[(size_t)m * 2048 + n]);
                    outf[(size_t)m * NHID + n] = scale[n] * mx + g;
                }
            }
        }
    }
}

// ---------------- MFMA flash attention, swapped-operand 32x32 structure.
// 1D grid 1024, bh-locality XCD swizzle: f = (bh&7) | (qt<<3) | ((bh>>3)<<7)
// so each XCD (wg%8) sees 8 bh's = 4MB of K/V (L2-resident).
// Q from Qc cols 1024..2047; Kb: [bh][s][d], Vt: [bh][d][s] (K pre-scaled by
// 0.125*log2e). mix -> Qc cols 0..1023.
//
// Softmax with m_r init 0 (T13: P bounded by 2^8, bf16-safe for this regime);
// QK accumulator PRELOADED with -m_r so the common path needs no per-score
// subtract. P row-sums computed on the MFMA pipe: accP = mfma(ones, P_frag)
// (A==1 -> D[i][q] = sum_k P[k][q], layout-independent).
#define LDS8(BASE, ROW, C8) \
    (*(const bf16x8*)&(BASE)[((ROW) << 6) + ((((C8) ^ ((ROW) & 7))) << 3)])

#define STAGE(KB, VB, J0) do {                                                   \
    _Pragma("unroll")                                                            \
    for (int it_ = 0; it_ < 2; ++it_) {                                          \
        const int ch_  = it_ * 256 + t;                                          \
        const int row_ = ch_ >> 3;                                               \
        const int c8_  = (ch_ & 7) ^ (row_ & 7);                                 \
        gload_lds16(Kbh + (size_t)((J0) + row_) * DIM + c8_ * 8,                 \
                    (char*)(KB) + ch_ * 16);                                     \
        gload_lds16(Vbh + (size_t)row_ * SEQ + (J0) + c8_ * 8,                   \
                    (char*)(VB) + ch_ * 16);                                     \
    }                                                                            \
} while (0)

#define TILE(KB, VB) do {                                                        \
    f32x16 sA, sB;                                                               \
    _Pragma("unroll")                                                            \
    for (int i_ = 0; i_ < 16; ++i_) { sA[i_] = negm; sB[i_] = negm; }            \
    __builtin_amdgcn_s_setprio(1);                                               \
    _Pragma("unroll")                                                            \
    for (int ds_ = 0; ds_ < 4; ++ds_) {                                          \
        bf16x8 kf0 = LDS8(KB, q31,      ds_ * 2 + g2);                           \
        bf16x8 kf1 = LDS8(KB, 32 + q31, ds_ * 2 + g2);                           \
        sA = __builtin_amdgcn_mfma_f32_32x32x16_bf16(kf0, qf[ds_], sA, 0, 0, 0); \
        sB = __builtin_amdgcn_mfma_f32_32x32x16_bf16(kf1, qf[ds_], sB, 0, 0, 0); \
    }                                                                            \
    __builtin_amdgcn_s_setprio(0);                                               \
    float tm[8];                                                                 \
    _Pragma("unroll")                                                            \
    for (int i_ = 0; i_ < 8; ++i_)                                               \
        tm[i_] = fmaxf(fmaxf(sA[2 * i_], sA[2 * i_ + 1]),                        \
                       fmaxf(sB[2 * i_], sB[2 * i_ + 1]));                       \
    _Pragma("unroll")                                                            \
    for (int i_ = 0; i_ < 4; ++i_) tm[i_] = fmaxf(tm[i_], tm[i_ + 4]);           \
    float mt = fmaxf(fmaxf(tm[0], tm[1]), fmaxf(tm[2], tm[3]));                  \
    mt = fmaxf(mt, __shfl_xor(mt, 32));                                          \
    if (!__all(mt <= 8.0f)) {                                                    \
        const float dm = fmaxf(mt, 0.0f);                                        \
        m_r += dm; negm = -m_r;                                                  \
        const float corr = exp2f(-dm);                                           \
        l_r *= corr;                                                             \
        accO0 = accO0 * corr; accO1 = accO1 * corr;                              \
        _Pragma("unroll")                                                        \
        for (int i_ = 0; i_ < 16; ++i_) { sA[i_] -= dm; sB[i_] -= dm; }          \
    }                                                                            \
    unsigned ppk[16];                                                            \
    _Pragma("unroll")                                                            \
    for (int p = 0; p < 8; ++p) {                                                \
        ppk[p]     = pk2(exp2f(sA[2 * p]), exp2f(sA[2 * p + 1]));                \
        ppk[8 + p] = pk2(exp2f(sB[2 * p]), exp2f(sB[2 * p + 1]));                \
    }                                                                            \
    f32x16 accP = {};                                                            \
    __builtin_amdgcn_s_setprio(1);                                               \
    _Pragma("unroll")                                                            \
    for (int kc = 0; kc < 4; ++kc) {                                             \
        const int i0 = 4 * (kc & 1) + 8 * (kc >> 1);                             \
        const unsigned sh0 = __shfl_xor(ppk[i0],     32);                        \
        const unsigned sh1 = __shfl_xor(ppk[i0 + 1], 32);                        \
        const unsigned sh2 = __shfl_xor(ppk[i0 + 2], 32);                        \
        const unsigned sh3 = __shfl_xor(ppk[i0 + 3], 32);                        \
        union { unsigned w[4]; bf16x8 v; } up;                                   \
        up.w[0] = g2 ? sh2 : ppk[i0];                                            \
        up.w[1] = g2 ? sh3 : ppk[i0 + 1];                                        \
        up.w[2] = g2 ? ppk[i0 + 2] : sh0;                                        \
        up.w[3] = g2 ? ppk[i0 + 3] : sh1;                                        \
        bf16x8 vf0 = LDS8(VB, q31,      kc * 2 + g2);                            \
        bf16x8 vf1 = LDS8(VB, 32 + q31, kc * 2 + g2);                            \
        accP  = __builtin_amdgcn_mfma_f32_32x32x16_bf16(aone.v, up.v, accP, 0, 0, 0);\
        accO0 = __builtin_amdgcn_mfma_f32_32x32x16_bf16(vf0, up.v, accO0, 0, 0, 0);\
        accO1 = __builtin_amdgcn_mfma_f32_32x32x16_bf16(vf1, up.v, accO1, 0, 0, 0);\
    }                                                                            \
    __builtin_amdgcn_s_setprio(0);                                               \
    l_r += accP[0];                                                              \
} while (0)

__global__ __launch_bounds__(256, 4) void k_attn(const unsigned short* __restrict__ Qc,
                                                 const unsigned short* __restrict__ Kb,
                                                 const unsigned short* __restrict__ Vt,
                                                 unsigned short* __restrict__ mixo)
{
    __shared__ unsigned short Ks0[4096], Ks1[4096];   // K[j][d], swizzled chunks
    __shared__ unsigned short Vs0[4096], Vs1[4096];   // V^T[d][j], swizzled
    const int t = threadIdx.x, wid = t >> 6, l = t & 63;
    const int g2 = l >> 5, q31 = l & 31;
    const int f = blockIdx.x;
    const int bh = (f & 7) + ((f >> 7) << 3);
    const int qt = (f >> 3) & 15;
    const int b = bh >> 4, h = bh & 15;
    const int s_q = qt * 128 + wid * 32 + q31;   // this lane's q row

    const unsigned short* Kbh = Kb + (size_t)bh * SEQ * DIM;
    const unsigned short* Vbh = Vt + (size_t)bh * DIM * SEQ;
    const unsigned short* Qrow = Qc + (size_t)(s_q * 4 + b) * 2048 + 1024 + h * 64;

    bf16x8 qf[4];
#pragma unroll
    for (int ds_ = 0; ds_ < 4; ++ds_)
        qf[ds_] = *(const bf16x8*)&Qrow[ds_ * 16 + g2 * 8];

    union { unsigned w[4]; bf16x8 v; } aone;         // bf16 1.0 x8
    aone.w[0] = aone.w[1] = aone.w[2] = aone.w[3] = 0x3F803F80u;

    f32x16 accO0 = {}, accO1 = {};             // d rows 0..31 / 32..63
    float m_r = 0.f, l_r = 0.f, negm = 0.f;    // T13: m starts at 0, P <= 2^8

    STAGE(Ks0, Vs0, 0);
#pragma unroll 1
    for (int j0 = 0; j0 < SEQ; j0 += 128) {
        __syncthreads();                       // buf0 loads done; buf1 free
        if (j0 + 64 < SEQ) STAGE(Ks1, Vs1, j0 + 64);
        TILE(Ks0, Vs0);
        __syncthreads();                       // buf1 loads done; buf0 free
        if (j0 + 128 < SEQ) STAGE(Ks0, Vs0, j0 + 128);
        TILE(Ks1, Vs1);
    }

    // ---- epilogue: mix[q][d] = accO^T / l   (C/D: col=q31, row=d)
    const float inv = 1.f / l_r;
    unsigned short* dst = mixo + (size_t)(s_q * 4 + b) * 2048 + h * 64;
#pragma unroll
    for (int reg = 0; reg < 16; reg += 2) {
        const int d0a = (reg & 3) + 8 * (reg >> 2) + 4 * g2;
        *(unsigned*)&dst[d0a]      = pk2(accO0[reg] * inv, accO0[reg + 1] * inv);
        *(unsigned*)&dst[32 + d0a] = pk2(accO1[reg] * inv, accO1[reg + 1] * inv);
    }
}

extern "C" void kernel_launch(void* const* d_in, const int* in_sizes, int n_in,
                              void* d_out, int out_size, void* d_ws, size_t ws_size,
                              hipStream_t stream)
{
    (void)in_sizes; (void)n_in; (void)out_size; (void)ws_size;
    const float* query  = (const float*)d_in[0];
    const float* key    = (const float*)d_in[1];
    const float* value  = (const float*)d_in[2];
    const float* qs_p   = (const float*)d_in[3];
    const float* ks_p   = (const float*)d_in[4];
    const float* vs_p   = (const float*)d_in[5];
    const float* vq_w   = (const float*)d_in[6];
    const float* vq_b   = (const float*)d_in[7];
    const float* q_w    = (const float*)d_in[8];
    const float* q_b    = (const float*)d_in[9];
    const float* k_w    = (const float*)d_in[10];
    const float* k_b    = (const float*)d_in[11];
    const float* v_w    = (const float*)d_in[12];
    const float* v_b    = (const float*)d_in[13];
    const float* r_w    = (const float*)d_in[14];
    const float* r_b    = (const float*)d_in[15];
    const float* r_gate = (const float*)d_in[16];

    float* fws = (float*)d_ws;
    float* sq = fws;
    float* sk = fws + 1024;
    float* sv = fws + 2048;
    float* rg = fws + 3072;
    float* cf = fws + 4096;                 // 2048 floats

    unsigned short* uws = (unsigned short*)(fws + 8192);
    unsigned short* Xq = uws;                                   // 8192*1024
    unsigned short* Xk = Xq + (size_t)MROWS * NHID;
    unsigned short* Xv = Xk + (size_t)MROWS * NHID;
    unsigned short* Wq = Xv + (size_t)MROWS * NHID;             // 1024*1024
    unsigned short* Wk = Wq + (size_t)NHID * NHID;
    unsigned short* Wv = Wk + (size_t)NHID * NHID;
    unsigned short* Wr = Wv + (size_t)NHID * NHID;              // 1024*2048
    unsigned short* Qc = Wr + (size_t)NHID * 2 * NHID;          // 8192*2048
    unsigned short* Kb = Qc + (size_t)MROWS * 2 * NHID;         // 64*2048*64
    unsigned short* Vb = Kb + (size_t)BATCH * HEADS * SEQ * DIM;

    k_cf<<<dim3(512), dim3(256), 0, stream>>>(vs_p, vq_w, vq_b, cf);
    k_scales<<<dim3(1), dim3(256), 0, stream>>>(qs_p, ks_p, r_gate, cf, sq, sk, sv, rg);

    k_f2b_all<<<dim3(29696), dim3(256), 0, stream>>>(query, key, value,
                                                     q_w, k_w, v_w, r_w,
                                                     Xq, Xk, Xv, Wq, Wk, Wv, Wr);

    k_gemm<1><<<dim3(64, 8), dim3(256), 0, stream>>>(Xk, Wk, k_b, sk, Kb, nullptr, nullptr, NHID);
    k_gemm<3><<<dim3(64, 8), dim3(256), 0, stream>>>(Xv, Wv, v_b, sv, Vb, nullptr, nullptr, NHID);
    k_gemm<0><<<dim3(64, 8), dim3(256), 0, stream>>>(Xq, Wq, q_b, sq, Qc, nullptr, nullptr, NHID);

    k_attn<<<dim3(1024), dim3(256), 0, stream>>>(Qc, Kb, Vb, Qc);

    k_gemm<2><<<dim3(64, 8), dim3(256), 0, stream>>>(Qc, Wr, r_b, rg, nullptr, (float*)d_out, Qc, 2 * NHID);
}

// Round 9
// 306.099 us; speedup vs baseline: 10.4143x; 1.1541x over previous
//
#include <hip/hip_runtime.h>
#include <hip/hip_bf16.h>
#include <math.h>

#define SEQ   2048
#define BATCH 4
#define NHID  1024
#define HEADS 16
#define DIM   64
#define MROWS (SEQ*BATCH)   // 8192
#define LOG2E 1.44269504f

typedef __attribute__((ext_vector_type(8)))  short bf16x8;
typedef __attribute__((ext_vector_type(4)))  float f32x4;
typedef __attribute__((ext_vector_type(16))) float f32x16;

__device__ __forceinline__ float sigf(float x) { return 1.0f / (1.0f + expf(-x)); }

__device__ __forceinline__ unsigned short f2b(float x) {
    unsigned int u = __float_as_uint(x);
    return (unsigned short)((u + 0x7FFFu + ((u >> 16) & 1u)) >> 16);
}
__device__ __forceinline__ float b2f(unsigned short h) {
    return __uint_as_float(((unsigned int)h) << 16);
}
__device__ __forceinline__ unsigned pk2(float lo, float hi) {
    __hip_bfloat162 h = __float22bfloat162_rn(make_float2(lo, hi));
    union { __hip_bfloat162 h; unsigned u; } cv; cv.h = h;
    return cv.u;
}
// Schraudolph-style fast 2^x: bitcast(int(x*2^23 + (127<<23 - C))).
// C=250000 centers the mantissa-linear error to ~±3% relative; softmax
// normalization averages this to ~1e-4 absolute on mix. Valid x in (-100,100).
__device__ __forceinline__ float fexp2(float x) {
    float tf = __builtin_fmaf(x, 8388608.0f, 1065103216.0f);
    return __uint_as_float((unsigned)(int)tf);
}
__device__ __forceinline__ void gload_lds16(const void* g, void* l) {
    __builtin_amdgcn_global_load_lds((const __attribute__((address_space(1))) void*)g,
                                     (__attribute__((address_space(3))) void*)l,
                                     16, 0, 0);
}

// ---------------- fused fp32 -> bf16 convert for all 7 tensors
__global__ __launch_bounds__(256) void k_f2b_all(const float* __restrict__ s0,
                                                 const float* __restrict__ s1,
                                                 const float* __restrict__ s2,
                                                 const float* __restrict__ s3,
                                                 const float* __restrict__ s4,
                                                 const float* __restrict__ s5,
                                                 const float* __restrict__ s6,
                                                 unsigned short* __restrict__ d0,
                                                 unsigned short* __restrict__ d1,
                                                 unsigned short* __restrict__ d2,
                                                 unsigned short* __restrict__ d3,
                                                 unsigned short* __restrict__ d4,
                                                 unsigned short* __restrict__ d5,
                                                 unsigned short* __restrict__ d6)
{
    int blk = blockIdx.x;
    const float* src; unsigned short* dst;
    if      (blk < 8192)  { src = s0; dst = d0; }
    else if (blk < 16384) { src = s1; dst = d1; blk -= 8192;  }
    else if (blk < 24576) { src = s2; dst = d2; blk -= 16384; }
    else if (blk < 25600) { src = s3; dst = d3; blk -= 24576; }
    else if (blk < 26624) { src = s4; dst = d4; blk -= 25600; }
    else if (blk < 27648) { src = s5; dst = d5; blk -= 26624; }
    else                  { src = s6; dst = d6; blk -= 27648; }
    const int i = (blk * 256 + threadIdx.x) * 4;
    float4 v = *(const float4*)(src + i);
    unsigned long long pack = (unsigned long long)f2b(v.x)
                            | ((unsigned long long)f2b(v.y) << 16)
                            | ((unsigned long long)f2b(v.z) << 32)
                            | ((unsigned long long)f2b(v.w) << 48);
    *(unsigned long long*)(dst + i) = pack;
}

// ---------------- prep: cf[j] = sigmoid(vs_p) . vq_w[j] + vq_b[j]
__global__ __launch_bounds__(256) void k_cf(const float* __restrict__ vs_p,
                                            const float* __restrict__ vq_w,
                                            const float* __restrict__ vq_b,
                                            float* __restrict__ cf)
{
    const int wave = threadIdx.x >> 6, lane = threadIdx.x & 63;
    const int j = blockIdx.x * 4 + wave;
    const float* w = vq_w + (size_t)j * NHID;
    float p = 0.f;
    for (int i = lane; i < NHID; i += 64) p += sigf(vs_p[i]) * w[i];
#pragma unroll
    for (int off = 32; off; off >>= 1) p += __shfl_down(p, off);
    if (lane == 0) cf[j] = p + vq_b[j];
}

// sk carries 0.125 (1/sqrt(dim)) and log2(e): softmax done in base-2 domain.
__global__ __launch_bounds__(256) void k_scales(const float* __restrict__ qs_p,
                                                const float* __restrict__ ks_p,
                                                const float* __restrict__ r_gate,
                                                const float* __restrict__ cf,
                                                float* __restrict__ sq, float* __restrict__ sk,
                                                float* __restrict__ sv, float* __restrict__ rg)
{
    for (int n = threadIdx.x; n < NHID; n += 256) {
        sq[n] = sigf(qs_p[n]);
        sk[n] = sigf(ks_p[n]) * (0.125f * LOG2E);
        rg[n] = sigf(r_gate[n]);
        sv[n] = sigf(cf[n + NHID]) * tanhf(cf[n]);
    }
}

// ---------------- bf16 MFMA GEMM, 128x128 tile, BK=64, T2 chunk-XOR swizzle.
// LDS rows are 128B (8 chunks of 16B); chunk c8 of row r holds global chunk
// c8^(r&7) (pre-swizzled global source, linear LDS dest — rule 21); fragment
// reads XOR back -> 2-way bank access (free).
// MODE 0: proj-> Qc right half (col 1024+n)
// MODE 1: proj-> K/V [b*16+h][s][d] bf16
// MODE 2: final: out fp32[m][n] = scale[n]*b2f(mixb[m*2048+n]) + gelu(acc+bias[n])
template<int MODE>
__global__ __launch_bounds__(256) void k_gemm(const unsigned short* __restrict__ A,
                                              const unsigned short* __restrict__ B,
                                              const float* __restrict__ bias,
                                              const float* __restrict__ scale,
                                              unsigned short* __restrict__ outb,
                                              float* __restrict__ outf,
                                              const unsigned short* __restrict__ mixb,
                                              int K)
{
    __shared__ unsigned short As[128 * 64];   // 16KB
    __shared__ unsigned short Bs[128 * 64];
    const int t = threadIdx.x;
    const int wid = t >> 6, lane = t & 63;
    const int wr = wid >> 1, wc = wid & 1;
    int wg = blockIdx.y * 64 + blockIdx.x;
    wg = (wg & 7) * 64 + (wg >> 3);          // 8 XCDs x 64 contiguous blocks
    const int bm = wg & 63, bn = wg >> 6;
    const unsigned short* Ab = A + (size_t)bm * 128 * K;
    const unsigned short* Bb = B + (size_t)bn * 128 * K;

    f32x4 acc[4][4] = {};

    for (int k0 = 0; k0 < K; k0 += 64) {
        __syncthreads();
#pragma unroll
        for (int it = 0; it < 4; ++it) {
            const int c   = it * 256 + t;
            const int row = c >> 3;
            const int g8  = (c & 7) ^ (row & 7);
            gload_lds16(Ab + (size_t)row * K + k0 + g8 * 8, (char*)As + c * 16);
            gload_lds16(Bb + (size_t)row * K + k0 + g8 * 8, (char*)Bs + c * 16);
        }
        __syncthreads();
#pragma unroll
        for (int ks = 0; ks < 2; ++ks) {
            bf16x8 af[4], bf[4];
#pragma unroll
            for (int mi = 0; mi < 4; ++mi) {
                const int r  = wr * 64 + mi * 16 + (lane & 15);
                const int c8 = (ks * 4 + (lane >> 4)) ^ (r & 7);
                af[mi] = *(const bf16x8*)&As[r * 64 + c8 * 8];
            }
#pragma unroll
            for (int ni = 0; ni < 4; ++ni) {
                const int r  = wc * 64 + ni * 16 + (lane & 15);
                const int c8 = (ks * 4 + (lane >> 4)) ^ (r & 7);
                bf[ni] = *(const bf16x8*)&Bs[r * 64 + c8 * 8];
            }
#pragma unroll
            for (int mi = 0; mi < 4; ++mi)
#pragma unroll
                for (int ni = 0; ni < 4; ++ni)
                    acc[mi][ni] = __builtin_amdgcn_mfma_f32_16x16x32_bf16(af[mi], bf[ni], acc[mi][ni], 0, 0, 0);
        }
    }

#pragma unroll
    for (int mi = 0; mi < 4; ++mi) {
#pragma unroll
        for (int r = 0; r < 4; ++r) {
            const int m = bm * 128 + wr * 64 + mi * 16 + (lane >> 4) * 4 + r;
#pragma unroll
            for (int ni = 0; ni < 4; ++ni) {
                const int n = bn * 128 + wc * 64 + ni * 16 + (lane & 15);
                const float a = acc[mi][ni][r];
                if constexpr (MODE == 0) {
                    const float v = scale[n] * (a + bias[n]);
                    outb[(size_t)m * 2048 + 1024 + n] = f2b(v);
                } else if constexpr (MODE == 1) {
                    const float v = scale[n] * (a + bias[n]);
                    const int s = m >> 2, b = m & 3, h = n >> 6, d = n & 63;
                    outb[((size_t)(b * HEADS + h) * SEQ + s) * DIM + d] = f2b(v);
                } else {
                    const float pre = a + bias[n];
                    const float g = pre * sigf(1.702f * pre);
                    const float mx = b2f(mixb[(size_t)m * 2048 + n]);
                    outf[(size_t)m * NHID + n] = scale[n] * mx + g;
                }
            }
        }
    }
}

// ---------------- V transpose: [bh][s][d] -> [bh][d][s], LDS-tiled 64x64.
// Read rows coalesced (128B), write rows coalesced (128B per d across 4 lanes);
// LDS pad 66 -> write phase conflict-free, read phase ~4-way on u16 (cheap).
__global__ __launch_bounds__(256) void k_vt(const unsigned short* __restrict__ Vin,
                                            unsigned short* __restrict__ Vout)
{
    __shared__ unsigned short Ls[64][66];
    const int bh = blockIdx.x >> 5, st = blockIdx.x & 31;
    const int t = threadIdx.x;
    const unsigned short* src = Vin + ((size_t)bh * SEQ + st * 64) * DIM;
    {
        const int s = t >> 2, d0 = (t & 3) * 16;
        *(bf16x8*)&Ls[s][d0]     = *(const bf16x8*)&src[s * DIM + d0];
        *(bf16x8*)&Ls[s][d0 + 8] = *(const bf16x8*)&src[s * DIM + d0 + 8];
    }
    __syncthreads();
    const int d = t >> 2, s0 = (t & 3) * 16;
    union { unsigned short h[16]; bf16x8 v[2]; } r;
#pragma unroll
    for (int i = 0; i < 16; ++i) r.h[i] = Ls[s0 + i][d];
    unsigned short* dst = Vout + ((size_t)bh * DIM + d) * SEQ + st * 64 + s0;
    *(bf16x8*)&dst[0] = r.v[0];
    *(bf16x8*)&dst[8] = r.v[1];
}

// ---------------- MFMA flash attention, swapped-operand 32x32 structure.
// 1D grid 1024, bh-locality XCD swizzle: f = (bh&7) | (qt<<3) | ((bh>>3)<<7).
// Q from Qc cols 1024..2047; Kb: [bh][s][d], Vt: [bh][d][s] (K pre-scaled by
// 0.125*log2e). mix -> Qc cols 0..1023.
#define LDS8(BASE, ROW, C8) \
    (*(const bf16x8*)&(BASE)[((ROW) << 6) + ((((C8) ^ ((ROW) & 7))) << 3)])

#define STAGE(KB, VB, J0) do {                                                   \
    _Pragma("unroll")                                                            \
    for (int it_ = 0; it_ < 2; ++it_) {                                          \
        const int ch_  = it_ * 256 + t;                                          \
        const int row_ = ch_ >> 3;                                               \
        const int c8_  = (ch_ & 7) ^ (row_ & 7);                                 \
        gload_lds16(Kbh + (size_t)((J0) + row_) * DIM + c8_ * 8,                 \
                    (char*)(KB) + ch_ * 16);                                     \
        gload_lds16(Vbh + (size_t)row_ * SEQ + (J0) + c8_ * 8,                   \
                    (char*)(VB) + ch_ * 16);                                     \
    }                                                                            \
} while (0)

#define TILE(KB, VB) do {                                                        \
    f32x16 sA, sB;                                                               \
    _Pragma("unroll")                                                            \
    for (int i_ = 0; i_ < 16; ++i_) { sA[i_] = negm; sB[i_] = negm; }            \
    __builtin_amdgcn_s_setprio(1);                                               \
    _Pragma("unroll")                                                            \
    for (int ds_ = 0; ds_ < 4; ++ds_) {                                          \
        bf16x8 kf0 = LDS8(KB, q31,      ds_ * 2 + g2);                           \
        bf16x8 kf1 = LDS8(KB, 32 + q31, ds_ * 2 + g2);                           \
        sA = __builtin_amdgcn_mfma_f32_32x32x16_bf16(kf0, qf[ds_], sA, 0, 0, 0); \
        sB = __builtin_amdgcn_mfma_f32_32x32x16_bf16(kf1, qf[ds_], sB, 0, 0, 0); \
    }                                                                            \
    __builtin_amdgcn_s_setprio(0);                                               \
    float tm[8];                                                                 \
    _Pragma("unroll")                                                            \
    for (int i_ = 0; i_ < 8; ++i_)                                               \
        tm[i_] = fmaxf(fmaxf(sA[2 * i_], sA[2 * i_ + 1]),                        \
                       fmaxf(sB[2 * i_], sB[2 * i_ + 1]));                       \
    _Pragma("unroll")                                                            \
    for (int i_ = 0; i_ < 4; ++i_) tm[i_] = fmaxf(tm[i_], tm[i_ + 4]);           \
    float mt = fmaxf(fmaxf(tm[0], tm[1]), fmaxf(tm[2], tm[3]));                  \
    mt = fmaxf(mt, __shfl_xor(mt, 32));                                          \
    if (!__all(mt <= 8.0f)) {                                                    \
        const float dm = fmaxf(mt, 0.0f);                                        \
        m_r += dm; negm = -m_r;                                                  \
        const float corr = exp2f(-dm);                                           \
        l_r *= corr;                                                             \
        accO0 = accO0 * corr; accO1 = accO1 * corr;                              \
        _Pragma("unroll")                                                        \
        for (int i_ = 0; i_ < 16; ++i_) { sA[i_] -= dm; sB[i_] -= dm; }          \
    }                                                                            \
    unsigned ppk[16];                                                            \
    _Pragma("unroll")                                                            \
    for (int p = 0; p < 8; ++p) {                                                \
        ppk[p]     = pk2(fexp2(sA[2 * p]), fexp2(sA[2 * p + 1]));                \
        ppk[8 + p] = pk2(fexp2(sB[2 * p]), fexp2(sB[2 * p + 1]));                \
    }                                                                            \
    f32x16 accP = {};                                                            \
    __builtin_amdgcn_s_setprio(1);                                               \
    _Pragma("unroll")                                                            \
    for (int kc = 0; kc < 4; ++kc) {                                             \
        const int i0 = 4 * (kc & 1) + 8 * (kc >> 1);                             \
        const unsigned sh0 = __shfl_xor(ppk[i0],     32);                        \
        const unsigned sh1 = __shfl_xor(ppk[i0 + 1], 32);                        \
        const unsigned sh2 = __shfl_xor(ppk[i0 + 2], 32);                        \
        const unsigned sh3 = __shfl_xor(ppk[i0 + 3], 32);                        \
        union { unsigned w[4]; bf16x8 v; } up;                                   \
        up.w[0] = g2 ? sh2 : ppk[i0];                                            \
        up.w[1] = g2 ? sh3 : ppk[i0 + 1];                                        \
        up.w[2] = g2 ? ppk[i0 + 2] : sh0;                                        \
        up.w[3] = g2 ? ppk[i0 + 3] : sh1;                                        \
        bf16x8 vf0 = LDS8(VB, q31,      kc * 2 + g2);                            \
        bf16x8 vf1 = LDS8(VB, 32 + q31, kc * 2 + g2);                            \
        accP  = __builtin_amdgcn_mfma_f32_32x32x16_bf16(aone.v, up.v, accP, 0, 0, 0);\
        accO0 = __builtin_amdgcn_mfma_f32_32x32x16_bf16(vf0, up.v, accO0, 0, 0, 0);\
        accO1 = __builtin_amdgcn_mfma_f32_32x32x16_bf16(vf1, up.v, accO1, 0, 0, 0);\
    }                                                                            \
    __builtin_amdgcn_s_setprio(0);                                               \
    l_r += accP[0];                                                              \
} while (0)

__global__ __launch_bounds__(256, 4) void k_attn(const unsigned short* __restrict__ Qc,
                                                 const unsigned short* __restrict__ Kb,
                                                 const unsigned short* __restrict__ Vt,
                                                 unsigned short* __restrict__ mixo)
{
    __shared__ unsigned short Ks0[4096], Ks1[4096];   // K[j][d], swizzled chunks
    __shared__ unsigned short Vs0[4096], Vs1[4096];   // V^T[d][j], swizzled
    const int t = threadIdx.x, wid = t >> 6, l = t & 63;
    const int g2 = l >> 5, q31 = l & 31;
    const int f = blockIdx.x;
    const int bh = (f & 7) + ((f >> 7) << 3);
    const int qt = (f >> 3) & 15;
    const int b = bh >> 4, h = bh & 15;
    const int s_q = qt * 128 + wid * 32 + q31;   // this lane's q row

    const unsigned short* Kbh = Kb + (size_t)bh * SEQ * DIM;
    const unsigned short* Vbh = Vt + (size_t)bh * DIM * SEQ;
    const unsigned short* Qrow = Qc + (size_t)(s_q * 4 + b) * 2048 + 1024 + h * 64;

    bf16x8 qf[4];
#pragma unroll
    for (int ds_ = 0; ds_ < 4; ++ds_)
        qf[ds_] = *(const bf16x8*)&Qrow[ds_ * 16 + g2 * 8];

    union { unsigned w[4]; bf16x8 v; } aone;         // bf16 1.0 x8
    aone.w[0] = aone.w[1] = aone.w[2] = aone.w[3] = 0x3F803F80u;

    f32x16 accO0 = {}, accO1 = {};             // d rows 0..31 / 32..63
    float m_r = 0.f, l_r = 0.f, negm = 0.f;    // T13: m starts at 0, P <= 2^8

    STAGE(Ks0, Vs0, 0);
#pragma unroll 1
    for (int j0 = 0; j0 < SEQ; j0 += 128) {
        __syncthreads();                       // buf0 loads done; buf1 free
        if (j0 + 64 < SEQ) STAGE(Ks1, Vs1, j0 + 64);
        TILE(Ks0, Vs0);
        __syncthreads();                       // buf1 loads done; buf0 free
        if (j0 + 128 < SEQ) STAGE(Ks0, Vs0, j0 + 128);
        TILE(Ks1, Vs1);
    }

    // ---- epilogue: mix[q][d] = accO^T / l   (C/D: col=q31, row=d)
    const float inv = 1.f / l_r;
    unsigned short* dst = mixo + (size_t)(s_q * 4 + b) * 2048 + h * 64;
#pragma unroll
    for (int reg = 0; reg < 16; reg += 2) {
        const int d0a = (reg & 3) + 8 * (reg >> 2) + 4 * g2;
        *(unsigned*)&dst[d0a]      = pk2(accO0[reg] * inv, accO0[reg + 1] * inv);
        *(unsigned*)&dst[32 + d0a] = pk2(accO1[reg] * inv, accO1[reg + 1] * inv);
    }
}

extern "C" void kernel_launch(void* const* d_in, const int* in_sizes, int n_in,
                              void* d_out, int out_size, void* d_ws, size_t ws_size,
                              hipStream_t stream)
{
    (void)in_sizes; (void)n_in; (void)out_size; (void)ws_size;
    const float* query  = (const float*)d_in[0];
    const float* key    = (const float*)d_in[1];
    const float* value  = (const float*)d_in[2];
    const float* qs_p   = (const float*)d_in[3];
    const float* ks_p   = (const float*)d_in[4];
    const float* vs_p   = (const float*)d_in[5];
    const float* vq_w   = (const float*)d_in[6];
    const float* vq_b   = (const float*)d_in[7];
    const float* q_w    = (const float*)d_in[8];
    const float* q_b    = (const float*)d_in[9];
    const float* k_w    = (const float*)d_in[10];
    const float* k_b    = (const float*)d_in[11];
    const float* v_w    = (const float*)d_in[12];
    const float* v_b    = (const float*)d_in[13];
    const float* r_w    = (const float*)d_in[14];
    const float* r_b    = (const float*)d_in[15];
    const float* r_gate = (const float*)d_in[16];

    float* fws = (float*)d_ws;
    float* sq = fws;
    float* sk = fws + 1024;
    float* sv = fws + 2048;
    float* rg = fws + 3072;
    float* cf = fws + 4096;                 // 2048 floats

    unsigned short* uws = (unsigned short*)(fws + 8192);
    unsigned short* Xq = uws;                                   // 8192*1024
    unsigned short* Xk = Xq + (size_t)MROWS * NHID;
    unsigned short* Xv = Xk + (size_t)MROWS * NHID;
    unsigned short* Wq = Xv + (size_t)MROWS * NHID;             // 1024*1024
    unsigned short* Wk = Wq + (size_t)NHID * NHID;
    unsigned short* Wv = Wk + (size_t)NHID * NHID;
    unsigned short* Wr = Wv + (size_t)NHID * NHID;              // 1024*2048
    unsigned short* Qc = Wr + (size_t)NHID * 2 * NHID;          // 8192*2048
    unsigned short* Kb = Qc + (size_t)MROWS * 2 * NHID;         // 64*2048*64
    unsigned short* Vb = Kb + (size_t)BATCH * HEADS * SEQ * DIM;
    unsigned short* Vtmp = Xq;   // aliases Xq (dead after Q-projection)

    k_cf<<<dim3(512), dim3(256), 0, stream>>>(vs_p, vq_w, vq_b, cf);
    k_scales<<<dim3(1), dim3(256), 0, stream>>>(qs_p, ks_p, r_gate, cf, sq, sk, sv, rg);

    k_f2b_all<<<dim3(29696), dim3(256), 0, stream>>>(query, key, value,
                                                     q_w, k_w, v_w, r_w,
                                                     Xq, Xk, Xv, Wq, Wk, Wv, Wr);

    // Q first (frees Xq), then K; V writes [bh][s][d] into Vtmp(=Xq), then transpose.
    k_gemm<0><<<dim3(64, 8), dim3(256), 0, stream>>>(Xq, Wq, q_b, sq, Qc, nullptr, nullptr, NHID);
    k_gemm<1><<<dim3(64, 8), dim3(256), 0, stream>>>(Xk, Wk, k_b, sk, Kb, nullptr, nullptr, NHID);
    k_gemm<1><<<dim3(64, 8), dim3(256), 0, stream>>>(Xv, Wv, v_b, sv, Vtmp, nullptr, nullptr, NHID);
    k_vt<<<dim3(2048), dim3(256), 0, stream>>>(Vtmp, Vb);

    k_attn<<<dim3(1024), dim3(256), 0, stream>>>(Qc, Kb, Vb, Qc);

    k_gemm<2><<<dim3(64, 8), dim3(256), 0, stream>>>(Qc, Wr, r_b, rg, nullptr, (float*)d_out, Qc, 2 * NHID);
}

// Round 10
// 294.232 us; speedup vs baseline: 10.8343x; 1.0403x over previous
//
#include <hip/hip_runtime.h>
#include <hip/hip_bf16.h>
#include <math.h>

#define SEQ   2048
#define BATCH 4
#define NHID  1024
#define HEADS 16
#define DIM   64
#define MROWS (SEQ*BATCH)   // 8192
#define LOG2E 1.44269504f

typedef __attribute__((ext_vector_type(8)))  short bf16x8;
typedef __attribute__((ext_vector_type(4)))  float f32x4;
typedef __attribute__((ext_vector_type(16))) float f32x16;

__device__ __forceinline__ float sigf(float x) { return 1.0f / (1.0f + expf(-x)); }

__device__ __forceinline__ unsigned short f2b(float x) {
    unsigned int u = __float_as_uint(x);
    return (unsigned short)((u + 0x7FFFu + ((u >> 16) & 1u)) >> 16);
}
__device__ __forceinline__ float b2f(unsigned short h) {
    return __uint_as_float(((unsigned int)h) << 16);
}
__device__ __forceinline__ unsigned pk2(float lo, float hi) {
    __hip_bfloat162 h = __float22bfloat162_rn(make_float2(lo, hi));
    union { __hip_bfloat162 h; unsigned u; } cv; cv.h = h;
    return cv.u;
}
// Schraudolph-style fast 2^x (±3% rel on P; normalization averages to ~1e-4).
__device__ __forceinline__ float fexp2(float x) {
    float tf = __builtin_fmaf(x, 8388608.0f, 1065103216.0f);
    return __uint_as_float((unsigned)(int)tf);
}
__device__ __forceinline__ void gload_lds16(const void* g, void* l) {
    __builtin_amdgcn_global_load_lds((const __attribute__((address_space(1))) void*)g,
                                     (__attribute__((address_space(3))) void*)l,
                                     16, 0, 0);
}

// ---------------- fused fp32 -> bf16 convert for all 7 tensors
__global__ __launch_bounds__(256) void k_f2b_all(const float* __restrict__ s0,
                                                 const float* __restrict__ s1,
                                                 const float* __restrict__ s2,
                                                 const float* __restrict__ s3,
                                                 const float* __restrict__ s4,
                                                 const float* __restrict__ s5,
                                                 const float* __restrict__ s6,
                                                 unsigned short* __restrict__ d0,
                                                 unsigned short* __restrict__ d1,
                                                 unsigned short* __restrict__ d2,
                                                 unsigned short* __restrict__ d3,
                                                 unsigned short* __restrict__ d4,
                                                 unsigned short* __restrict__ d5,
                                                 unsigned short* __restrict__ d6)
{
    int blk = blockIdx.x;
    const float* src; unsigned short* dst;
    if      (blk < 8192)  { src = s0; dst = d0; }
    else if (blk < 16384) { src = s1; dst = d1; blk -= 8192;  }
    else if (blk < 24576) { src = s2; dst = d2; blk -= 16384; }
    else if (blk < 25600) { src = s3; dst = d3; blk -= 24576; }
    else if (blk < 26624) { src = s4; dst = d4; blk -= 25600; }
    else if (blk < 27648) { src = s5; dst = d5; blk -= 26624; }
    else                  { src = s6; dst = d6; blk -= 27648; }
    const int i = (blk * 256 + threadIdx.x) * 4;
    float4 v = *(const float4*)(src + i);
    unsigned long long pack = (unsigned long long)f2b(v.x)
                            | ((unsigned long long)f2b(v.y) << 16)
                            | ((unsigned long long)f2b(v.z) << 32)
                            | ((unsigned long long)f2b(v.w) << 48);
    *(unsigned long long*)(dst + i) = pack;
}

// ---------------- prep: cf[j] = sigmoid(vs_p) . vq_w[j] + vq_b[j]
__global__ __launch_bounds__(256) void k_cf(const float* __restrict__ vs_p,
                                            const float* __restrict__ vq_w,
                                            const float* __restrict__ vq_b,
                                            float* __restrict__ cf)
{
    const int wave = threadIdx.x >> 6, lane = threadIdx.x & 63;
    const int j = blockIdx.x * 4 + wave;
    const float* w = vq_w + (size_t)j * NHID;
    float p = 0.f;
    for (int i = lane; i < NHID; i += 64) p += sigf(vs_p[i]) * w[i];
#pragma unroll
    for (int off = 32; off; off >>= 1) p += __shfl_down(p, off);
    if (lane == 0) cf[j] = p + vq_b[j];
}

// sk carries 0.125 (1/sqrt(dim)) and log2(e): softmax done in base-2 domain.
__global__ __launch_bounds__(256) void k_scales(const float* __restrict__ qs_p,
                                                const float* __restrict__ ks_p,
                                                const float* __restrict__ r_gate,
                                                const float* __restrict__ cf,
                                                float* __restrict__ sq, float* __restrict__ sk,
                                                float* __restrict__ sv, float* __restrict__ rg)
{
    for (int n = threadIdx.x; n < NHID; n += 256) {
        sq[n] = sigf(qs_p[n]);
        sk[n] = sigf(ks_p[n]) * (0.125f * LOG2E);
        rg[n] = sigf(r_gate[n]);
        sv[n] = sigf(cf[n + NHID]) * tanhf(cf[n]);
    }
}

// ---------------- shared GEMM body pieces (128x128 tile, BK=64, T2 swizzle)
#define GEMM_BODY(Ab, Bb, K)                                                     \
    f32x4 acc[4][4] = {};                                                        \
    for (int k0 = 0; k0 < (K); k0 += 64) {                                       \
        __syncthreads();                                                         \
        _Pragma("unroll")                                                        \
        for (int it = 0; it < 4; ++it) {                                         \
            const int c   = it * 256 + t;                                        \
            const int row = c >> 3;                                              \
            const int g8  = (c & 7) ^ (row & 7);                                 \
            gload_lds16(Ab + (size_t)row * (K) + k0 + g8 * 8, (char*)As + c * 16);\
            gload_lds16(Bb + (size_t)row * (K) + k0 + g8 * 8, (char*)Bs + c * 16);\
        }                                                                        \
        __syncthreads();                                                         \
        _Pragma("unroll")                                                        \
        for (int ks = 0; ks < 2; ++ks) {                                         \
            bf16x8 af[4], bf[4];                                                 \
            _Pragma("unroll")                                                    \
            for (int mi = 0; mi < 4; ++mi) {                                     \
                const int r  = wr * 64 + mi * 16 + (lane & 15);                  \
                const int c8 = (ks * 4 + (lane >> 4)) ^ (r & 7);                 \
                af[mi] = *(const bf16x8*)&As[r * 64 + c8 * 8];                   \
            }                                                                    \
            _Pragma("unroll")                                                    \
            for (int ni = 0; ni < 4; ++ni) {                                     \
                const int r  = wc * 64 + ni * 16 + (lane & 15);                  \
                const int c8 = (ks * 4 + (lane >> 4)) ^ (r & 7);                 \
                bf[ni] = *(const bf16x8*)&Bs[r * 64 + c8 * 8];                   \
            }                                                                    \
            _Pragma("unroll")                                                    \
            for (int mi = 0; mi < 4; ++mi)                                       \
                _Pragma("unroll")                                                \
                for (int ni = 0; ni < 4; ++ni)                                   \
                    acc[mi][ni] = __builtin_amdgcn_mfma_f32_16x16x32_bf16(af[mi], bf[ni], acc[mi][ni], 0, 0, 0); \
        }                                                                        \
    }

// ---------------- merged Q/K/V projection GEMM: grid 1536, seg = wg/512.
// seg 0: -> Qc right half (col 1024+n).  seg 1/2: -> [b*16+h][s][d].
__global__ __launch_bounds__(256) void k_proj3(const unsigned short* __restrict__ A0,
                                               const unsigned short* __restrict__ A1,
                                               const unsigned short* __restrict__ A2,
                                               const unsigned short* __restrict__ W0,
                                               const unsigned short* __restrict__ W1,
                                               const unsigned short* __restrict__ W2,
                                               const float* __restrict__ b0,
                                               const float* __restrict__ b1,
                                               const float* __restrict__ b2,
                                               const float* __restrict__ c0,
                                               const float* __restrict__ c1,
                                               const float* __restrict__ c2,
                                               unsigned short* __restrict__ o0,
                                               unsigned short* __restrict__ o1,
                                               unsigned short* __restrict__ o2)
{
    __shared__ unsigned short As[128 * 64];
    __shared__ unsigned short Bs[128 * 64];
    const int t = threadIdx.x;
    const int wid = t >> 6, lane = t & 63;
    const int wr = wid >> 1, wc = wid & 1;
    int f = blockIdx.x;
    int wg = (f & 7) * 192 + (f >> 3);       // 8 XCDs x 192 contiguous blocks
    const int seg = wg / 512, inner = wg - seg * 512;
    const int bm = inner & 63, bn = inner >> 6;
    const unsigned short* A = seg == 0 ? A0 : seg == 1 ? A1 : A2;
    const unsigned short* W = seg == 0 ? W0 : seg == 1 ? W1 : W2;
    const float* bias  = seg == 0 ? b0 : seg == 1 ? b1 : b2;
    const float* scale = seg == 0 ? c0 : seg == 1 ? c1 : c2;
    unsigned short* outb = seg == 0 ? o0 : seg == 1 ? o1 : o2;
    const unsigned short* Ab = A + (size_t)bm * 128 * NHID;
    const unsigned short* Bb = W + (size_t)bn * 128 * NHID;

    GEMM_BODY(Ab, Bb, NHID)

#pragma unroll
    for (int mi = 0; mi < 4; ++mi) {
#pragma unroll
        for (int r = 0; r < 4; ++r) {
            const int m = bm * 128 + wr * 64 + mi * 16 + (lane >> 4) * 4 + r;
#pragma unroll
            for (int ni = 0; ni < 4; ++ni) {
                const int n = bn * 128 + wc * 64 + ni * 16 + (lane & 15);
                const float v = scale[n] * (acc[mi][ni][r] + bias[n]);
                if (seg == 0) {
                    outb[(size_t)m * 2048 + 1024 + n] = f2b(v);
                } else {
                    const int s = m >> 2, b = m & 3, h = n >> 6, d = n & 63;
                    outb[((size_t)(b * HEADS + h) * SEQ + s) * DIM + d] = f2b(v);
                }
            }
        }
    }
}

// ---------------- final GEMM (K=2048) + gelu/gate epilogue
__global__ __launch_bounds__(256) void k_final(const unsigned short* __restrict__ A,
                                               const unsigned short* __restrict__ W,
                                               const float* __restrict__ bias,
                                               const float* __restrict__ rg,
                                               float* __restrict__ outf,
                                               const unsigned short* __restrict__ mixb)
{
    __shared__ unsigned short As[128 * 64];
    __shared__ unsigned short Bs[128 * 64];
    const int t = threadIdx.x;
    const int wid = t >> 6, lane = t & 63;
    const int wr = wid >> 1, wc = wid & 1;
    int wg = blockIdx.y * 64 + blockIdx.x;
    wg = (wg & 7) * 64 + (wg >> 3);
    const int bm = wg & 63, bn = wg >> 6;
    const int K = 2 * NHID;
    const unsigned short* Ab = A + (size_t)bm * 128 * K;
    const unsigned short* Bb = W + (size_t)bn * 128 * K;

    GEMM_BODY(Ab, Bb, K)

#pragma unroll
    for (int mi = 0; mi < 4; ++mi) {
#pragma unroll
        for (int r = 0; r < 4; ++r) {
            const int m = bm * 128 + wr * 64 + mi * 16 + (lane >> 4) * 4 + r;
#pragma unroll
            for (int ni = 0; ni < 4; ++ni) {
                const int n = bn * 128 + wc * 64 + ni * 16 + (lane & 15);
                const float pre = acc[mi][ni][r] + bias[n];
                const float g = pre * sigf(1.702f * pre);
                const float mx = b2f(mixb[(size_t)m * 2048 + n]);
                outf[(size_t)m * NHID + n] = rg[n] * mx + g;
            }
        }
    }
}

// ---------------- V transpose: [bh][s][d] -> [bh][d][pos(s)], pos = s with
// bits 2<->3 swapped. This stores V^T columns in PV-contraction order so the
// attn PV B-fragment is the lane's own registers (no cross-lane exchange).
__global__ __launch_bounds__(256) void k_vt(const unsigned short* __restrict__ Vin,
                                            unsigned short* __restrict__ Vout)
{
    __shared__ unsigned short Ls[64][66];
    const int bh = blockIdx.x >> 5, st = blockIdx.x & 31;
    const int t = threadIdx.x;
    const unsigned short* src = Vin + ((size_t)bh * SEQ + st * 64) * DIM;
    {
        const int s = t >> 2, d0 = (t & 3) * 16;
        *(bf16x8*)&Ls[s][d0]     = *(const bf16x8*)&src[s * DIM + d0];
        *(bf16x8*)&Ls[s][d0 + 8] = *(const bf16x8*)&src[s * DIM + d0 + 8];
    }
    __syncthreads();
    const int d = t >> 2, s0 = (t & 3) * 16;
    union { unsigned short h[16]; unsigned long long q[4]; } r;
#pragma unroll
    for (int i = 0; i < 16; ++i) r.h[i] = Ls[s0 + i][d];
    unsigned short* dst = Vout + ((size_t)bh * DIM + d) * SEQ + st * 64 + s0;
    *(unsigned long long*)&dst[0]  = r.q[0];   // s0+0..3   -> pos +0
    *(unsigned long long*)&dst[8]  = r.q[1];   // s0+4..7   -> pos +8
    *(unsigned long long*)&dst[4]  = r.q[2];   // s0+8..11  -> pos +4
    *(unsigned long long*)&dst[12] = r.q[3];   // s0+12..15 -> pos +12
}

// ---------------- MFMA flash attention, swapped-operand 32x32 structure.
// 1D grid 1024, bh-locality XCD swizzle: f = (bh&7) | (qt<<3) | ((bh>>3)<<7).
// Q from Qc cols 1024..2047; Kb: [bh][s][d], Vt: [bh][d][pos(s)] (K pre-scaled
// by 0.125*log2e). mix -> Qc cols 0..1023.
// PV B-fragment for step kc = ppk[4kc..4kc+3] (own regs; V column order pos(j)
// makes the k<->j bijection line up — derived from verified C/D + B layouts).
#define LDS8(BASE, ROW, C8) \
    (*(const bf16x8*)&(BASE)[((ROW) << 6) + ((((C8) ^ ((ROW) & 7))) << 3)])

#define STAGE(KB, VB, J0) do {                                                   \
    _Pragma("unroll")                                                            \
    for (int it_ = 0; it_ < 2; ++it_) {                                          \
        const int ch_  = it_ * 256 + t;                                          \
        const int row_ = ch_ >> 3;                                               \
        const int c8_  = (ch_ & 7) ^ (row_ & 7);                                 \
        gload_lds16(Kbh + (size_t)((J0) + row_) * DIM + c8_ * 8,                 \
                    (char*)(KB) + ch_ * 16);                                     \
        gload_lds16(Vbh + (size_t)row_ * SEQ + (J0) + c8_ * 8,                   \
                    (char*)(VB) + ch_ * 16);                                     \
    }                                                                            \
} while (0)

#define TILE(KB, VB) do {                                                        \
    f32x16 sA, sB;                                                               \
    _Pragma("unroll")                                                            \
    for (int i_ = 0; i_ < 16; ++i_) { sA[i_] = negm; sB[i_] = negm; }            \
    __builtin_amdgcn_s_setprio(1);                                               \
    _Pragma("unroll")                                                            \
    for (int ds_ = 0; ds_ < 4; ++ds_) {                                          \
        bf16x8 kf0 = LDS8(KB, q31,      ds_ * 2 + g2);                           \
        bf16x8 kf1 = LDS8(KB, 32 + q31, ds_ * 2 + g2);                           \
        sA = __builtin_amdgcn_mfma_f32_32x32x16_bf16(kf0, qf[ds_], sA, 0, 0, 0); \
        sB = __builtin_amdgcn_mfma_f32_32x32x16_bf16(kf1, qf[ds_], sB, 0, 0, 0); \
    }                                                                            \
    __builtin_amdgcn_s_setprio(0);                                               \
    float tm[8];                                                                 \
    _Pragma("unroll")                                                            \
    for (int i_ = 0; i_ < 8; ++i_)                                               \
        tm[i_] = fmaxf(fmaxf(sA[2 * i_], sA[2 * i_ + 1]),                        \
                       fmaxf(sB[2 * i_], sB[2 * i_ + 1]));                       \
    _Pragma("unroll")                                                            \
    for (int i_ = 0; i_ < 4; ++i_) tm[i_] = fmaxf(tm[i_], tm[i_ + 4]);           \
    float mt = fmaxf(fmaxf(tm[0], tm[1]), fmaxf(tm[2], tm[3]));                  \
    mt = fmaxf(mt, __shfl_xor(mt, 32));                                          \
    if (!__all(mt <= 8.0f)) {                                                    \
        const float dm = fmaxf(mt, 0.0f);                                        \
        m_r += dm; negm = -m_r;                                                  \
        const float corr = exp2f(-dm);                                           \
        l_r *= corr;                                                             \
        accO0 = accO0 * corr; accO1 = accO1 * corr;                              \
        _Pragma("unroll")                                                        \
        for (int i_ = 0; i_ < 16; ++i_) { sA[i_] -= dm; sB[i_] -= dm; }          \
    }                                                                            \
    unsigned ppk[16];                                                            \
    _Pragma("unroll")                                                            \
    for (int p = 0; p < 8; ++p) {                                                \
        ppk[p]     = pk2(fexp2(sA[2 * p]), fexp2(sA[2 * p + 1]));                \
        ppk[8 + p] = pk2(fexp2(sB[2 * p]), fexp2(sB[2 * p + 1]));                \
    }                                                                            \
    f32x16 accP = {};                                                            \
    __builtin_amdgcn_s_setprio(1);                                               \
    _Pragma("unroll")                                                            \
    for (int kc = 0; kc < 4; ++kc) {                                             \
        union { unsigned w[4]; bf16x8 v; } up;                                   \
        up.w[0] = ppk[4 * kc + 0];                                               \
        up.w[1] = ppk[4 * kc + 1];                                               \
        up.w[2] = ppk[4 * kc + 2];                                               \
        up.w[3] = ppk[4 * kc + 3];                                               \
        bf16x8 vf0 = LDS8(VB, q31,      kc * 2 + g2);                            \
        bf16x8 vf1 = LDS8(VB, 32 + q31, kc * 2 + g2);                            \
        accP  = __builtin_amdgcn_mfma_f32_32x32x16_bf16(aone.v, up.v, accP, 0, 0, 0);\
        accO0 = __builtin_amdgcn_mfma_f32_32x32x16_bf16(vf0, up.v, accO0, 0, 0, 0);\
        accO1 = __builtin_amdgcn_mfma_f32_32x32x16_bf16(vf1, up.v, accO1, 0, 0, 0);\
    }                                                                            \
    __builtin_amdgcn_s_setprio(0);                                               \
    l_r += accP[0];                                                              \
} while (0)

__global__ __launch_bounds__(256, 4) void k_attn(const unsigned short* __restrict__ Qc,
                                                 const unsigned short* __restrict__ Kb,
                                                 const unsigned short* __restrict__ Vt,
                                                 unsigned short* __restrict__ mixo)
{
    __shared__ unsigned short Ks0[4096], Ks1[4096];   // K[j][d], swizzled chunks
    __shared__ unsigned short Vs0[4096], Vs1[4096];   // V^T[d][pos], swizzled
    const int t = threadIdx.x, wid = t >> 6, l = t & 63;
    const int g2 = l >> 5, q31 = l & 31;
    const int f = blockIdx.x;
    const int bh = (f & 7) + ((f >> 7) << 3);
    const int qt = (f >> 3) & 15;
    const int b = bh >> 4, h = bh & 15;
    const int s_q = qt * 128 + wid * 32 + q31;   // this lane's q row

    const unsigned short* Kbh = Kb + (size_t)bh * SEQ * DIM;
    const unsigned short* Vbh = Vt + (size_t)bh * DIM * SEQ;
    const unsigned short* Qrow = Qc + (size_t)(s_q * 4 + b) * 2048 + 1024 + h * 64;

    bf16x8 qf[4];
#pragma unroll
    for (int ds_ = 0; ds_ < 4; ++ds_)
        qf[ds_] = *(const bf16x8*)&Qrow[ds_ * 16 + g2 * 8];

    union { unsigned w[4]; bf16x8 v; } aone;         // bf16 1.0 x8
    aone.w[0] = aone.w[1] = aone.w[2] = aone.w[3] = 0x3F803F80u;

    f32x16 accO0 = {}, accO1 = {};             // d rows 0..31 / 32..63
    float m_r = 0.f, l_r = 0.f, negm = 0.f;    // T13: m starts at 0, P <= 2^8

    STAGE(Ks0, Vs0, 0);
#pragma unroll 1
    for (int j0 = 0; j0 < SEQ; j0 += 128) {
        __syncthreads();                       // buf0 loads done; buf1 free
        if (j0 + 64 < SEQ) STAGE(Ks1, Vs1, j0 + 64);
        TILE(Ks0, Vs0);
        __syncthreads();                       // buf1 loads done; buf0 free
        if (j0 + 128 < SEQ) STAGE(Ks0, Vs0, j0 + 128);
        TILE(Ks1, Vs1);
    }

    // ---- epilogue: mix[q][d] = accO^T / l   (C/D: col=q31, row=d)
    const float inv = 1.f / l_r;
    unsigned short* dst = mixo + (size_t)(s_q * 4 + b) * 2048 + h * 64;
#pragma unroll
    for (int reg = 0; reg < 16; reg += 2) {
        const int d0a = (reg & 3) + 8 * (reg >> 2) + 4 * g2;
        *(unsigned*)&dst[d0a]      = pk2(accO0[reg] * inv, accO0[reg + 1] * inv);
        *(unsigned*)&dst[32 + d0a] = pk2(accO1[reg] * inv, accO1[reg + 1] * inv);
    }
}

extern "C" void kernel_launch(void* const* d_in, const int* in_sizes, int n_in,
                              void* d_out, int out_size, void* d_ws, size_t ws_size,
                              hipStream_t stream)
{
    (void)in_sizes; (void)n_in; (void)out_size; (void)ws_size;
    const float* query  = (const float*)d_in[0];
    const float* key    = (const float*)d_in[1];
    const float* value  = (const float*)d_in[2];
    const float* qs_p   = (const float*)d_in[3];
    const float* ks_p   = (const float*)d_in[4];
    const float* vs_p   = (const float*)d_in[5];
    const float* vq_w   = (const float*)d_in[6];
    const float* vq_b   = (const float*)d_in[7];
    const float* q_w    = (const float*)d_in[8];
    const float* q_b    = (const float*)d_in[9];
    const float* k_w    = (const float*)d_in[10];
    const float* k_b    = (const float*)d_in[11];
    const float* v_w    = (const float*)d_in[12];
    const float* v_b    = (const float*)d_in[13];
    const float* r_w    = (const float*)d_in[14];
    const float* r_b    = (const float*)d_in[15];
    const float* r_gate = (const float*)d_in[16];

    float* fws = (float*)d_ws;
    float* sq = fws;
    float* sk = fws + 1024;
    float* sv = fws + 2048;
    float* rg = fws + 3072;
    float* cf = fws + 4096;                 // 2048 floats

    unsigned short* uws = (unsigned short*)(fws + 8192);
    unsigned short* Xq = uws;                                   // 8192*1024
    unsigned short* Xk = Xq + (size_t)MROWS * NHID;
    unsigned short* Xv = Xk + (size_t)MROWS * NHID;
    unsigned short* Wq = Xv + (size_t)MROWS * NHID;             // 1024*1024
    unsigned short* Wk = Wq + (size_t)NHID * NHID;
    unsigned short* Wv = Wk + (size_t)NHID * NHID;
    unsigned short* Wr = Wv + (size_t)NHID * NHID;              // 1024*2048
    unsigned short* Qc = Wr + (size_t)NHID * 2 * NHID;          // 8192*2048
    unsigned short* Kb = Qc + (size_t)MROWS * 2 * NHID;         // 64*2048*64
    unsigned short* Vb = Kb + (size_t)BATCH * HEADS * SEQ * DIM;
    unsigned short* Vtmp = Kb + (size_t)BATCH * HEADS * SEQ * DIM
                              + (size_t)BATCH * HEADS * SEQ * DIM;  // after Vb

    k_cf<<<dim3(512), dim3(256), 0, stream>>>(vs_p, vq_w, vq_b, cf);
    k_scales<<<dim3(1), dim3(256), 0, stream>>>(qs_p, ks_p, r_gate, cf, sq, sk, sv, rg);

    k_f2b_all<<<dim3(29696), dim3(256), 0, stream>>>(query, key, value,
                                                     q_w, k_w, v_w, r_w,
                                                     Xq, Xk, Xv, Wq, Wk, Wv, Wr);

    // merged Q/K/V projections (seg 0/1/2); V -> Vtmp [bh][s][d], then transpose.
    k_proj3<<<dim3(1536), dim3(256), 0, stream>>>(Xq, Xk, Xv, Wq, Wk, Wv,
                                                  q_b, k_b, v_b, sq, sk, sv,
                                                  Qc, Kb, Vtmp);
    k_vt<<<dim3(2048), dim3(256), 0, stream>>>(Vtmp, Vb);

    k_attn<<<dim3(1024), dim3(256), 0, stream>>>(Qc, Kb, Vb, Qc);

    k_final<<<dim3(64, 8), dim3(256), 0, stream>>>(Qc, Wr, r_b, rg, (float*)d_out, Qc);
}